// Round 17
// baseline (1076.756 us; speedup 1.0000x reference)
//
#include <hip/hip_runtime.h>
#include <hip/hip_bf16.h>
#include <math.h>

#define BB 8
#define SEQN 1025
#define DD 1024
#define HH 8
#define HD 128
#define LL 2
#define MROWS (BB*SEQN)     // 8200
#define NBUCKET 64

using short8 = __attribute__((ext_vector_type(8))) short;
using f32x4  = __attribute__((ext_vector_type(4))) float;
using f32x16 = __attribute__((ext_vector_type(16))) float;

__device__ __forceinline__ float silu_f(float x) { return x / (1.f + expf(-x)); }

__device__ __forceinline__ float bf2f(ushort u) {
  union { uint i; float f; } x; x.i = ((uint)u) << 16; return x.f;
}
__device__ __forceinline__ ushort f2bf(float f) {
  __hip_bfloat16 b = __float2bfloat16(f);
  return *reinterpret_cast<ushort*>(&b);
}
__device__ __forceinline__ void gll16(const void* g, void* l) {
  __builtin_amdgcn_global_load_lds((const __attribute__((address_space(1))) void*)g,
                                   (__attribute__((address_space(3))) void*)l, 16, 0, 0);
}
__device__ __forceinline__ uint pkbf(float lo, float hi) {
  uint r;
  asm("v_cvt_pk_bf16_f32 %0, %1, %2" : "=v"(r) : "v"(lo), "v"(hi));
  return r;
}
__device__ __forceinline__ f32x16 z16() {
  f32x16 v;
#pragma unroll
  for (int i = 0; i < 16; ++i) v[i] = 0.f;
  return v;
}

// ---------------- weight transpose+convert: W[K,N] f32 -> Wt[N,K] bf16 ----------------
__global__ __launch_bounds__(256) void wtrans(const float* __restrict__ W,
                                              ushort* __restrict__ Wt, int K, int N) {
  __shared__ float tile[32][33];
  int tid = threadIdx.x;
  int tx = tid & 31, ty = tid >> 5;           // 32 x 8
  int n0 = blockIdx.x * 32, k0 = blockIdx.y * 32;
#pragma unroll
  for (int r = 0; r < 32; r += 8)
    tile[ty + r][tx] = W[(size_t)(k0 + ty + r) * N + n0 + tx];
  __syncthreads();
#pragma unroll
  for (int r = 0; r < 32; r += 8)
    Wt[(size_t)(n0 + ty + r) * K + k0 + tx] = f2bf(tile[tx][ty + r]);
}

// ---------------- rel-attn bias, TRANSPOSED + bf16: biasT[b][j][i] ----------------
__global__ __launch_bounds__(256) void bias_kernel(const int* __restrict__ ts,
    const float* __restrict__ ts_w, const float* __restrict__ pos_w,
    ushort* __restrict__ biasT)
{
  int i = blockIdx.x * 256 + threadIdx.x;
  int j = blockIdx.y;
  int b = blockIdx.z;
  if (i >= SEQN) return;
  int ip1 = i + 1; if (ip1 > SEQN - 1) ip1 = SEQN - 1;
  long long t1 = (long long)ts[b * SEQN + ip1];
  long long t0 = (long long)ts[b * SEQN + j];
  long long d = t1 - t0;
  if (d < 0) d = -d;
  if (d < 1) d = 1;
  int bucket = (int)(logf((float)d) / 0.301f);
  if (bucket < 0) bucket = 0;
  if (bucket > NBUCKET) bucket = NBUCKET;
  biasT[((size_t)(b * SEQN + j)) * SEQN + i] = f2bf(pos_w[j - i + SEQN - 1] + ts_w[bucket]);
}

// ---------------- layer-0 LN fused with seqs->h copy ----------------
__global__ __launch_bounds__(256) void lnh_kernel(const float* __restrict__ in,
    float* __restrict__ hout, ushort* __restrict__ out) {
  int row = blockIdx.x;
  int tid = threadIdx.x;
  const float* x = in + (size_t)row * DD;
  float4 v = *(const float4*)&x[tid * 4];
  float s = v.x + v.y + v.z + v.w;
  float ss = v.x*v.x + v.y*v.y + v.z*v.z + v.w*v.w;
#pragma unroll
  for (int off = 32; off >= 1; off >>= 1) { s += __shfl_xor(s, off); ss += __shfl_xor(ss, off); }
  __shared__ float red0[4], red1[4];
  if ((tid & 63) == 0) { red0[tid >> 6] = s; red1[tid >> 6] = ss; }
  __syncthreads();
  s = red0[0] + red0[1] + red0[2] + red0[3];
  ss = red1[0] + red1[1] + red1[2] + red1[3];
  float mu = s * (1.f / DD);
  float var = fmaxf(ss * (1.f / DD) - mu * mu, 0.f);
  float inv = 1.f / sqrtf(var + 1e-8f);
  *(float4*)&hout[(size_t)row * DD + tid * 4] = v;
  ushort4 o;
  o.x = f2bf((v.x - mu) * inv); o.y = f2bf((v.y - mu) * inv);
  o.z = f2bf((v.z - mu) * inv); o.w = f2bf((v.w - mu) * inv);
  *(ushort4*)&out[(size_t)row * DD + tid * 4] = o;
}

// ---------------- row norms (f32 in, bf16 out) ----------------
__global__ __launch_bounds__(256) void ln_kernel(const float* __restrict__ in,
                                                 ushort* __restrict__ out) {
  int row = blockIdx.x;
  int tid = threadIdx.x;
  const float* x = in + (size_t)row * DD;
  float4 v = *(const float4*)&x[tid * 4];
  float s = v.x + v.y + v.z + v.w;
  float ss = v.x*v.x + v.y*v.y + v.z*v.z + v.w*v.w;
#pragma unroll
  for (int off = 32; off >= 1; off >>= 1) { s += __shfl_xor(s, off); ss += __shfl_xor(ss, off); }
  __shared__ float red0[4], red1[4];
  if ((tid & 63) == 0) { red0[tid >> 6] = s; red1[tid >> 6] = ss; }
  __syncthreads();
  s = red0[0] + red0[1] + red0[2] + red0[3];
  ss = red1[0] + red1[1] + red1[2] + red1[3];
  float mu = s * (1.f / DD);
  float var = fmaxf(ss * (1.f / DD) - mu * mu, 0.f);
  float inv = 1.f / sqrtf(var + 1e-8f);
  ushort4 o;
  o.x = f2bf((v.x - mu) * inv); o.y = f2bf((v.y - mu) * inv);
  o.z = f2bf((v.z - mu) * inv); o.w = f2bf((v.w - mu) * inv);
  *(ushort4*)&out[(size_t)row * DD + tid * 4] = o;
}

__global__ __launch_bounds__(256) void rms_kernel(const float* __restrict__ in,
                                                  ushort* __restrict__ out) {
  int row = blockIdx.x;
  int tid = threadIdx.x;
  const float* x = in + (size_t)row * DD;
  float4 v = *(const float4*)&x[tid * 4];
  float ss = v.x*v.x + v.y*v.y + v.z*v.z + v.w*v.w;
#pragma unroll
  for (int off = 32; off >= 1; off >>= 1) ss += __shfl_xor(ss, off);
  __shared__ float red1[4];
  if ((tid & 63) == 0) red1[tid >> 6] = ss;
  __syncthreads();
  ss = red1[0] + red1[1] + red1[2] + red1[3];
  float inv = 1.f / sqrtf(ss * (1.f / DD) + 1e-8f);
  ushort4 o;
  o.x = f2bf(v.x * inv); o.y = f2bf(v.y * inv);
  o.z = f2bf(v.z * inv); o.w = f2bf(v.w * inv);
  *(ushort4*)&out[(size_t)row * DD + tid * 4] = o;
}

// out[d] = u[d] * layernorm(av)[d]   (av bf16, u bf16 from act, out bf16)
__global__ __launch_bounds__(256) void uln_kernel(const ushort* __restrict__ av,
    const ushort* __restrict__ act, ushort* __restrict__ out) {
  int row = blockIdx.x;
  int tid = threadIdx.x;
  ushort4 ub = *(const ushort4*)&av[(size_t)row * DD + tid * 4];
  float4 v;
  v.x = bf2f(ub.x); v.y = bf2f(ub.y); v.z = bf2f(ub.z); v.w = bf2f(ub.w);
  float s = v.x + v.y + v.z + v.w;
  float ss = v.x*v.x + v.y*v.y + v.z*v.z + v.w*v.w;
#pragma unroll
  for (int off = 32; off >= 1; off >>= 1) { s += __shfl_xor(s, off); ss += __shfl_xor(ss, off); }
  __shared__ float red0[4], red1[4];
  if ((tid & 63) == 0) { red0[tid >> 6] = s; red1[tid >> 6] = ss; }
  __syncthreads();
  s = red0[0] + red0[1] + red0[2] + red0[3];
  ss = red1[0] + red1[1] + red1[2] + red1[3];
  float mu = s * (1.f / DD);
  float var = fmaxf(ss * (1.f / DD) - mu * mu, 0.f);
  float inv = 1.f / sqrtf(var + 1e-8f);
  ushort4 uu = *(const ushort4*)&act[(size_t)row * 4096 + 3072 + tid * 4];
  ushort4 o;
  o.x = f2bf(bf2f(uu.x) * (v.x - mu) * inv);
  o.y = f2bf(bf2f(uu.y) * (v.y - mu) * inv);
  o.z = f2bf(bf2f(uu.z) * (v.z - mu) * inv);
  o.w = f2bf(bf2f(uu.w) * (v.w - mu) * inv);
  *(ushort4*)&out[(size_t)row * DD + tid * 4] = o;
}

// ---------------- bf16 MFMA GEMM (BK=32, 3-buffer depth-2 pipeline), 256 thr ----
// N=1024 MODE1 GEMMs (out-proj, fc2): f32 out += AW + bvec.
__global__ __launch_bounds__(256) void mgemm1(const ushort* __restrict__ A,
    const ushort* __restrict__ Bt, const float* __restrict__ bvec,
    float* __restrict__ Cout, int M, int Nn, int K)
{
  __shared__ ushort As[3][4096];
  __shared__ ushort Bs[3][4096];
  const int tid  = threadIdx.x;
  const int lane = tid & 63, wave = tid >> 6;
  const int wm = wave >> 1, wn = wave & 1;
  const int lrow = lane & 15, lk = lane >> 4;
  const int bm = blockIdx.y * 128, bn = blockIdx.x * 128;

  const ushort* Aga[2]; const ushort* Bga[2];
  ushort* Ada[2]; ushort* Bda[2];
#pragma unroll
  for (int i = 0; i < 2; ++i) {
    int c = tid + 256 * i;
    int row = c >> 2, s = c & 3;
    int sc = s ^ ((row >> 1) & 3);
    Aga[i] = A  + (size_t)(bm + row) * K + sc * 8;
    Bga[i] = Bt + (size_t)(bn + row) * K + sc * 8;
    Ada[i] = &As[0][c * 8];
    Bda[i] = &Bs[0][c * 8];
  }

  int aoff[4], boff[4];
#pragma unroll
  for (int m = 0; m < 4; ++m)
    aoff[m] = (wm * 64 + m * 16 + lrow) * 32 + ((lk ^ ((lrow >> 1) & 3)) * 8);
#pragma unroll
  for (int n = 0; n < 4; ++n)
    boff[n] = (wn * 64 + n * 16 + lrow) * 32 + ((lk ^ ((lrow >> 1) & 3)) * 8);

  f32x4 acc[4][4];
#pragma unroll
  for (int m = 0; m < 4; ++m)
#pragma unroll
    for (int n = 0; n < 4; ++n) acc[m][n] = (f32x4){0.f, 0.f, 0.f, 0.f};

  const int nk = K >> 5;
#pragma unroll
  for (int t = 0; t < 2; ++t) {
#pragma unroll
    for (int i = 0; i < 2; ++i) {
      gll16(Aga[i] + (t << 5), Ada[i] + t * 4096);
      gll16(Bga[i] + (t << 5), Bda[i] + t * 4096);
    }
  }
  int cur = 0, nxt2 = 2;
  for (int kt = 0; kt < nk; ++kt) {
    if (kt + 1 < nk) {
      asm volatile("s_waitcnt vmcnt(4)" ::: "memory");
    } else {
      asm volatile("s_waitcnt vmcnt(0)" ::: "memory");
    }
    __builtin_amdgcn_s_barrier();
    __builtin_amdgcn_sched_barrier(0);
    if (kt + 2 < nk) {
      const int ko = (kt + 2) << 5;
      const int bo = nxt2 * 4096;
#pragma unroll
      for (int i = 0; i < 2; ++i) {
        gll16(Aga[i] + ko, Ada[i] + bo);
        gll16(Bga[i] + ko, Bda[i] + bo);
      }
    }
    __builtin_amdgcn_s_setprio(1);
    {
      short8 af[4], bfr[4];
      const int co = cur * 4096;
#pragma unroll
      for (int m = 0; m < 4; ++m) af[m]  = *(const short8*)&As[0][co + aoff[m]];
#pragma unroll
      for (int n = 0; n < 4; ++n) bfr[n] = *(const short8*)&Bs[0][co + boff[n]];
#pragma unroll
      for (int m = 0; m < 4; ++m)
#pragma unroll
        for (int n = 0; n < 4; ++n)
          acc[m][n] = __builtin_amdgcn_mfma_f32_16x16x32_bf16(af[m], bfr[n], acc[m][n], 0, 0, 0);
    }
    __builtin_amdgcn_s_setprio(0);
    __builtin_amdgcn_sched_barrier(0);
    cur = (cur == 2) ? 0 : cur + 1;
    nxt2 = (nxt2 == 2) ? 0 : nxt2 + 1;
  }

  const int colbase = bn + wn * 64 + lrow;
  const int rowbase = bm + wm * 64 + lk * 4;
#pragma unroll
  for (int m = 0; m < 4; ++m) {
    int row0 = rowbase + m * 16;
#pragma unroll
    for (int n = 0; n < 4; ++n) {
      int col = colbase + n * 16;
      float bv = bvec[col];
#pragma unroll
      for (int r = 0; r < 4; ++r) {
        int row = row0 + r;
        if (row < M) {
          float* p = Cout + (size_t)row * Nn + col;
          *p += acc[m][n][r] + bv;
        }
      }
    }
  }
}

// ------- 8-phase wide bf16 MFMA GEMM: 256x256, BK=64, 8 waves, counted vmcnt -------
// R17: sched_barrier(0) pins REMOVED (m141: order-pinning defeats the compiler's
// fine-grained lgkmcnt scheduling; raw s_barrier + "memory"-clobbered vmcnt asm
// still order LDS ops across sync points). Schedule otherwise identical to R15.
template<int MODE>
__global__ __launch_bounds__(512, 2) void mgemm8(const ushort* __restrict__ A,
    const ushort* __restrict__ Bt, const float* __restrict__ bvec,
    void* __restrict__ Cout, int M, int Nn, int K)
{
  __shared__ ushort LS[65536];   // 128 KB
  const int tid = threadIdx.x;
  const int lane = tid & 63, wave = tid >> 6;
  const int wm = wave >> 2, wn = wave & 3;       // 2m x 4n; wave tile 128x64
  const int lrow = lane & 15, lk = lane >> 4;
  const int bm = blockIdx.y * 256;

  const ushort* srcA[2]; const ushort* srcB[2];
  int ldsA[2], ldsB[2];
#pragma unroll
  for (int i = 0; i < 2; ++i) {
    int c = tid + 512 * i, row = c >> 2, s = c & 3;
    int sw = (s ^ ((row >> 1) & 3)) * 8;
    srcA[i] = A + (size_t)(bm + row) * K + sw;
    ldsA[i] = c * 8;
    int gr;
    if (MODE == 3) {
      gr = blockIdx.x * 128 + (row >> 5) * 16 + ((row >> 4) & 1) * 2048 + (row & 15);
    } else {
      gr = blockIdx.x * 256 + row;
    }
    srcB[i] = Bt + (size_t)gr * K + sw;
    ldsB[i] = c * 8;
  }
  int aoff[8], boff[4];
#pragma unroll
  for (int m = 0; m < 8; ++m)
    aoff[m] = (wm * 128 + m * 16 + lrow) * 32 + ((lk ^ ((lrow >> 1) & 3)) * 8);
#pragma unroll
  for (int n = 0; n < 4; ++n)
    boff[n] = (wn * 64 + n * 16 + lrow) * 32 + ((lk ^ ((lrow >> 1) & 3)) * 8);

  f32x4 acc[8][4];
#pragma unroll
  for (int m = 0; m < 8; ++m)
#pragma unroll
    for (int n = 0; n < 4; ++n) acc[m][n] = (f32x4){0.f, 0.f, 0.f, 0.f};

  const int NT = K >> 6;   // 16

#define STG_A(T, H, B)                                                        \
  { _Pragma("unroll")                                                         \
    for (int i = 0; i < 2; ++i)                                               \
      gll16(srcA[i] + ((T) << 6) + ((H) << 5),                                \
            (void*)&LS[((B) * 2 + (H)) * 8192 + ldsA[i]]); }
#define STG_B(T, H, B)                                                        \
  { _Pragma("unroll")                                                         \
    for (int i = 0; i < 2; ++i)                                               \
      gll16(srcB[i] + ((T) << 6) + ((H) << 5),                                \
            (void*)&LS[32768 + ((B) * 2 + (H)) * 8192 + ldsB[i]]); }

#define TILE4(T, B)                                                           \
  {                                                                           \
    const int t_ = (T);                                                       \
    { int ts = (t_ + 1 < NT) ? t_ + 1 : NT - 1; STG_A(ts, 1, (B) ^ 1); }      \
    asm volatile("s_waitcnt vmcnt(10)" ::: "memory");                         \
    __builtin_amdgcn_s_barrier();                                             \
    short8 bfr[4];                                                            \
    _Pragma("unroll")                                                         \
    for (int n = 0; n < 4; ++n)                                               \
      bfr[n] = *(const short8*)&LS[32768 + ((B) * 2 + 0) * 8192 + boff[n]];   \
    {                                                                         \
      short8 af[4];                                                           \
      _Pragma("unroll")                                                       \
      for (int mi = 0; mi < 4; ++mi)                                          \
        af[mi] = *(const short8*)&LS[((B) * 2 + 0) * 8192 + aoff[mi]];        \
      __builtin_amdgcn_s_setprio(1);                                          \
      _Pragma("unroll")                                                       \
      for (int mi = 0; mi < 4; ++mi)                                          \
        _Pragma("unroll")                                                     \
        for (int n = 0; n < 4; ++n)                                           \
          acc[mi][n] = __builtin_amdgcn_mfma_f32_16x16x32_bf16(af[mi], bfr[n], acc[mi][n], 0, 0, 0); \
      __builtin_amdgcn_s_setprio(0);                                          \
    }                                                                         \
    { int ts = (t_ + 1 < NT) ? t_ + 1 : NT - 1; STG_B(ts, 1, (B) ^ 1); }      \
    {                                                                         \
      short8 af[4];                                                           \
      _Pragma("unroll")                                                       \
      for (int mi = 0; mi < 4; ++mi)                                          \
        af[mi] = *(const short8*)&LS[((B) * 2 + 0) * 8192 + aoff[4 + mi]];    \
      __builtin_amdgcn_s_setprio(1);                                          \
      _Pragma("unroll")                                                       \
      for (int mi = 0; mi < 4; ++mi)                                          \
        _Pragma("unroll")                                                     \
        for (int n = 0; n < 4; ++n)                                           \
          acc[4 + mi][n] = __builtin_amdgcn_mfma_f32_16x16x32_bf16(af[mi], bfr[n], acc[4 + mi][n], 0, 0, 0); \
      __builtin_amdgcn_s_setprio(0);                                          \
    }                                                                         \
    __builtin_amdgcn_s_barrier();                                             \
    { int ts = (t_ + 2 < NT) ? t_ + 2 : NT - 1; STG_A(ts, 0, (B)); }          \
    asm volatile("s_waitcnt vmcnt(10)" ::: "memory");                         \
    __builtin_amdgcn_s_barrier();                                             \
    _Pragma("unroll")                                                         \
    for (int n = 0; n < 4; ++n)                                               \
      bfr[n] = *(const short8*)&LS[32768 + ((B) * 2 + 1) * 8192 + boff[n]];   \
    {                                                                         \
      short8 af[4];                                                           \
      _Pragma("unroll")                                                       \
      for (int mi = 0; mi < 4; ++mi)                                          \
        af[mi] = *(const short8*)&LS[((B) * 2 + 1) * 8192 + aoff[mi]];        \
      __builtin_amdgcn_s_setprio(1);                                          \
      _Pragma("unroll")                                                       \
      for (int mi = 0; mi < 4; ++mi)                                          \
        _Pragma("unroll")                                                     \
        for (int n = 0; n < 4; ++n)                                           \
          acc[mi][n] = __builtin_amdgcn_mfma_f32_16x16x32_bf16(af[mi], bfr[n], acc[mi][n], 0, 0, 0); \
      __builtin_amdgcn_s_setprio(0);                                          \
    }                                                                         \
    { int ts = (t_ + 2 < NT) ? t_ + 2 : NT - 1; STG_B(ts, 0, (B)); }          \
    {                                                                         \
      short8 af[4];                                                           \
      _Pragma("unroll")                                                       \
      for (int mi = 0; mi < 4; ++mi)                                          \
        af[mi] = *(const short8*)&LS[((B) * 2 + 1) * 8192 + aoff[4 + mi]];    \
      __builtin_amdgcn_s_setprio(1);                                          \
      _Pragma("unroll")                                                       \
      for (int mi = 0; mi < 4; ++mi)                                          \
        _Pragma("unroll")                                                     \
        for (int n = 0; n < 4; ++n)                                           \
          acc[4 + mi][n] = __builtin_amdgcn_mfma_f32_16x16x32_bf16(af[mi], bfr[n], acc[4 + mi][n], 0, 0, 0); \
      __builtin_amdgcn_s_setprio(0);                                          \
    }                                                                         \
    __builtin_amdgcn_s_barrier();                                             \
  }

  STG_A(0, 0, 0); STG_B(0, 0, 0); STG_A(0, 1, 0); STG_B(0, 1, 0);
  STG_A(1, 0, 1); STG_B(1, 0, 1);
  for (int tt = 0; tt < NT; tt += 2) {
    TILE4(tt, 0);
    TILE4(tt + 1, 1);
  }
#undef TILE4
#undef STG_A
#undef STG_B

  const int rowb0 = bm + wm * 128 + lk * 4;
  if (MODE == 0) {
    const int colb0 = blockIdx.x * 256 + wn * 64 + lrow;
    __hip_bfloat16* Cb = (__hip_bfloat16*)Cout;
#pragma unroll
    for (int m = 0; m < 8; ++m) {
      int row0 = rowb0 + m * 16;
#pragma unroll
      for (int n = 0; n < 4; ++n) {
        int col = colb0 + n * 16;
#pragma unroll
        for (int r = 0; r < 4; ++r) {
          int row = row0 + r;
          if (row < M)
            Cb[(size_t)row * Nn + col] = __float2bfloat16(silu_f(acc[m][n][r]));
        }
      }
    }
  } else {
    __hip_bfloat16* Cb = (__hip_bfloat16*)Cout;   // gated [M][2048]
#pragma unroll
    for (int q = 0; q < 2; ++q) {
      int vcol = blockIdx.x * 128 + (2 * wn + q) * 16 + lrow;
      float bvv = bvec[vcol];
      float bvg = bvec[vcol + 2048];
#pragma unroll
      for (int m = 0; m < 8; ++m) {
        int row0 = rowb0 + m * 16;
#pragma unroll
        for (int r = 0; r < 4; ++r) {
          int row = row0 + r;
          if (row < M) {
            float v = acc[m][2 * q][r] + bvv;
            float g = acc[m][2 * q + 1][r] + bvg;
            Cb[(size_t)row * 2048 + vcol] = __float2bfloat16(silu_f(g) * v);
          }
        }
      }
    }
  }
}

// ---------------- MFMA causal silu-attention (double-buffered K/V, 1 barrier/tile) --
__global__ __launch_bounds__(256) void attn_kernel(const ushort* __restrict__ act,
    const ushort* __restrict__ biasT, ushort* __restrict__ av)
{
  __shared__ __align__(16) char KL[16384];   // 2 bufs x [32 j][128 d] swizzled
  __shared__ __align__(16) char VL[16640];   // 2 bufs x subtiled V (8320 each)
  const int tid = threadIdx.x;
  const int l = tid & 63, w = tid >> 6;
  const int qi = (int)(gridDim.x - 1 - blockIdx.x);
  const int i0 = qi * 128;
  const int h = blockIdx.y, b = blockIdx.z;
  const int lo31 = l & 31, hi = l >> 5;

  const int jlim = (i0 + 128 < SEQN) ? i0 + 128 : SEQN;
  const int nt = (jlim + 31) >> 5;

  const int gi_q = i0 + w * 32 + lo31;
  const int gi_qc = gi_q < SEQN ? gi_q : SEQN - 1;
  const size_t actB = (size_t)b * SEQN;
  const ushort* qrow = act + (actB + gi_qc) * 4096 + h * HD;
  short8 qreg[8];
#pragma unroll
  for (int dc = 0; dc < 8; ++dc)
    qreg[dc] = *(const short8*)(qrow + dc * 16 + hi * 8);

  f32x16 acc[4];
#pragma unroll
  for (int dt = 0; dt < 4; ++dt) acc[dt] = z16();

  const int id0 = tid, id1 = tid + 256;
  const int j_0 = id0 >> 4, c8_0 = (id0 & 15) * 8;
  const int j_1 = id1 >> 4, c8_1 = (id1 & 15) * 8;
  char* kw0 = KL + j_0 * 256 + (((id0 & 15) ^ (j_0 & 15)) << 4);
  char* kw1 = KL + j_1 * 256 + (((id1 & 15) ^ (j_1 & 15)) << 4);
  char* vw0 = VL + ((id0 & 15) >> 1) * 1040 + j_0 * 32 + (id0 & 1) * 16;
  char* vw1 = VL + ((id1 & 15) >> 1) * 1040 + j_1 * 32 + (id1 & 1) * 16;
  const uint vbase0 = (uint)(size_t)(__attribute__((address_space(3))) char*)
      (VL + ((l >> 4) & 1) * 1040 + hi * 256 + (l & 15) * 8);

  short8 kr0, kr1, vr0, vr1;
  {
    const ushort* p0 = act + (actB + j_0) * 4096 + 1024 + h * HD + c8_0;
    const ushort* p1 = act + (actB + j_1) * 4096 + 1024 + h * HD + c8_1;
    kr0 = *(const short8*)p0; vr0 = *(const short8*)(p0 + 1024);
    kr1 = *(const short8*)p1; vr1 = *(const short8*)(p1 + 1024);
  }
  const float invN = 1.f / (float)SEQN;
  const int gi0w = i0 + w * 32;

  for (int t = 0; t < nt; ++t) {
    const int j0 = t * 32;
    const int kb = (t & 1) * 8192;
    const int vb = (t & 1) * 8320;
    *(short8*)(kw0 + kb) = kr0; *(short8*)(kw1 + kb) = kr1;
    *(short8*)(vw0 + vb) = vr0; *(short8*)(vw1 + vb) = vr1;
    __syncthreads();
    if (t + 1 < nt) {
      const ushort* p0 = act + (actB + j0 + 32 + j_0) * 4096 + 1024 + h * HD + c8_0;
      const ushort* p1 = act + (actB + j0 + 32 + j_1) * 4096 + 1024 + h * HD + c8_1;
      kr0 = *(const short8*)p0; vr0 = *(const short8*)(p0 + 1024);
      kr1 = *(const short8*)p1; vr1 = *(const short8*)(p1 + 1024);
    }
    if (j0 <= gi0w + 31 && gi0w < SEQN) {
      float bv[16];
#pragma unroll
      for (int r = 0; r < 16; ++r) {
        int j = (r & 3) + 8 * (r >> 2) + 4 * hi;
        int gj = j0 + j;
        int gjc = gj < SEQN ? gj : SEQN - 1;
        bv[r] = bf2f(biasT[(actB + gjc) * SEQN + gi_qc]);
      }
      f32x16 st = z16();
#pragma unroll
      for (int dc = 0; dc < 8; ++dc) {
        short8 kf = *(const short8*)(KL + kb + lo31 * 256 + ((((dc << 1) + hi) ^ (lo31 & 15)) << 4));
        st = __builtin_amdgcn_mfma_f32_32x32x16_bf16(kf, qreg[dc], st, 0, 0, 0);
      }
      float p[16];
#pragma unroll
      for (int r = 0; r < 16; ++r) {
        int j = (r & 3) + 8 * (r >> 2) + 4 * hi;
        int gj = j0 + j;
        float s = st[r] + bv[r];
        float pw = s * __builtin_amdgcn_rcpf(1.f + __expf(-s)) * invN;
        p[r] = ((gj <= gi_q) && (gi_q < SEQN)) ? pw : 0.f;
      }
      short8 paf[2];
#pragma unroll
      for (int g = 0; g < 2; ++g) {
        uint w0 = pkbf(p[g * 8 + 0], p[g * 8 + 1]);
        uint w2 = pkbf(p[g * 8 + 4], p[g * 8 + 5]);
        uint w1 = pkbf(p[g * 8 + 2], p[g * 8 + 3]);
        uint w3 = pkbf(p[g * 8 + 6], p[g * 8 + 7]);
        asm volatile("v_permlane32_swap_b32 %0, %1" : "+v"(w0), "+v"(w2));
        asm volatile("v_permlane32_swap_b32 %0, %1" : "+v"(w1), "+v"(w3));
        union UF { uint u[4]; short8 s; } uf;
        uf.u[0] = w0; uf.u[1] = w1; uf.u[2] = w2; uf.u[3] = w3;
        paf[g] = uf.s;
      }
      const uint vbase = vbase0 + vb;
      uint64_t v00, v01, v02, v03, v10, v11, v12, v13, v20, v21, v22, v23, v30, v31, v32, v33;
      asm volatile(
        "ds_read_b64_tr_b16 %0, %16 offset:0\n\t"
        "ds_read_b64_tr_b16 %1, %16 offset:128\n\t"
        "ds_read_b64_tr_b16 %2, %16 offset:512\n\t"
        "ds_read_b64_tr_b16 %3, %16 offset:640\n\t"
        "ds_read_b64_tr_b16 %4, %16 offset:2080\n\t"
        "ds_read_b64_tr_b16 %5, %16 offset:2208\n\t"
        "ds_read_b64_tr_b16 %6, %16 offset:2592\n\t"
        "ds_read_b64_tr_b16 %7, %16 offset:2720\n\t"
        "ds_read_b64_tr_b16 %8, %16 offset:4160\n\t"
        "ds_read_b64_tr_b16 %9, %16 offset:4288\n\t"
        "ds_read_b64_tr_b16 %10, %16 offset:4672\n\t"
        "ds_read_b64_tr_b16 %11, %16 offset:4800\n\t"
        "ds_read_b64_tr_b16 %12, %16 offset:6240\n\t"
        "ds_read_b64_tr_b16 %13, %16 offset:6368\n\t"
        "ds_read_b64_tr_b16 %14, %16 offset:6752\n\t"
        "ds_read_b64_tr_b16 %15, %16 offset:6880\n\t"
        "s_waitcnt lgkmcnt(0)"
        : "=v"(v00), "=v"(v01), "=v"(v02), "=v"(v03),
          "=v"(v10), "=v"(v11), "=v"(v12), "=v"(v13),
          "=v"(v20), "=v"(v21), "=v"(v22), "=v"(v23),
          "=v"(v30), "=v"(v31), "=v"(v32), "=v"(v33)
        : "v"(vbase) : "memory");
      union UV { uint64_t q[2]; short8 s; };
      { UV uv; uv.q[0] = v00; uv.q[1] = v01;
        acc[0] = __builtin_amdgcn_mfma_f32_32x32x16_bf16(paf[0], uv.s, acc[0], 0, 0, 0); }
      { UV uv; uv.q[0] = v02; uv.q[1] = v03;
        acc[0] = __builtin_amdgcn_mfma_f32_32x32x16_bf16(paf[1], uv.s, acc[0], 0, 0, 0); }
      { UV uv; uv.q[0] = v10; uv.q[1] = v11;
        acc[1] = __builtin_amdgcn_mfma_f32_32x32x16_bf16(paf[0], uv.s, acc[1], 0, 0, 0); }
      { UV uv; uv.q[0] = v12; uv.q[1] = v13;
        acc[1] = __builtin_amdgcn_mfma_f32_32x32x16_bf16(paf[1], uv.s, acc[1], 0, 0, 0); }
      { UV uv; uv.q[0] = v20; uv.q[1] = v21;
        acc[2] = __builtin_amdgcn_mfma_f32_32x32x16_bf16(paf[0], uv.s, acc[2], 0, 0, 0); }
      { UV uv; uv.q[0] = v22; uv.q[1] = v23;
        acc[2] = __builtin_amdgcn_mfma_f32_32x32x16_bf16(paf[1], uv.s, acc[2], 0, 0, 0); }
      { UV uv; uv.q[0] = v30; uv.q[1] = v31;
        acc[3] = __builtin_amdgcn_mfma_f32_32x32x16_bf16(paf[0], uv.s, acc[3], 0, 0, 0); }
      { UV uv; uv.q[0] = v32; uv.q[1] = v33;
        acc[3] = __builtin_amdgcn_mfma_f32_32x32x16_bf16(paf[1], uv.s, acc[3], 0, 0, 0); }
    }
  }
#pragma unroll
  for (int dt = 0; dt < 4; ++dt) {
#pragma unroll
    for (int r = 0; r < 16; ++r) {
      int q = (r & 3) + 8 * (r >> 2) + 4 * hi;
      int gi = i0 + w * 32 + q;
      if (gi < SEQN)
        av[(actB + gi) * DD + h * HD + dt * 32 + lo31] = f2bf(acc[dt][r]);
    }
  }
}

// ---------------- launch ----------------
extern "C" void kernel_launch(void* const* d_in, const int* in_sizes, int n_in,
                              void* d_out, int out_size, void* d_ws, size_t ws_size,
                              hipStream_t stream) {
  const float* seqs  = (const float*)d_in[0];
  const int*   ts    = (const int*)d_in[2];
  const float* qkvuW = (const float*)d_in[3];
  const float* outW  = (const float*)d_in[4];
  const float* outB  = (const float*)d_in[5];
  const float* tsW   = (const float*)d_in[6];
  const float* posW  = (const float*)d_in[7];
  const float* fc1W  = (const float*)d_in[8];
  const float* fc1B  = (const float*)d_in[9];
  const float* fc2W  = (const float*)d_in[10];
  const float* fc2B  = (const float*)d_in[11];
  float* h = (float*)d_out;
  char* ws = (char*)d_ws;

  ushort* xn    = (ushort*)(ws);                 // 8448*1024*2  = 17,301,504
  ushort* act   = (ushort*)(ws + 17301504);      // 8200*4096*2  = 67,174,400
  ushort* gated = (ushort*)(ws + 84475904);      // 8320*2048*2  = 34,078,720
  ushort* biasT = (ushort*)(ws + 118554624);     // 8*1025*1025*2= 16,810,000
  ushort* av    = (ushort*)(ws + 152174624);     // 8200*1024*2  = 16,793,600
  ushort* wq    = (ushort*)(ws + 185761824);     // 4096*1024*2
  ushort* wo    = (ushort*)(ws + 194150432);     // 1024*1024*2
  ushort* wf1   = (ushort*)(ws + 196247584);     // 4096*1024*2
  ushort* wf2   = (ushort*)(ws + 204636192);     // 1024*2048*2  (end 208,830,496)

  for (int l = 0; l < LL; l++) {
    wtrans<<<dim3(128, 32), 256, 0, stream>>>(qkvuW + (size_t)l * DD * 4096, wq, DD, 4096);
    wtrans<<<dim3(32, 32),  256, 0, stream>>>(outW  + (size_t)l * DD * DD,   wo, DD, DD);
    wtrans<<<dim3(128, 32), 256, 0, stream>>>(fc1W  + (size_t)l * DD * 4096, wf1, DD, 4096);
    wtrans<<<dim3(32, 64),  256, 0, stream>>>(fc2W  + (size_t)l * 2048 * DD, wf2, 2048, DD);

    bias_kernel<<<dim3(5, SEQN, BB), 256, 0, stream>>>(
        ts, tsW + l * (NBUCKET + 1), posW + l * (2 * SEQN - 1), biasT);

    if (l == 0)
      lnh_kernel<<<MROWS, 256, 0, stream>>>(seqs, h, xn);   // h = seqs; xn = LN(seqs)
    else
      ln_kernel<<<MROWS, 256, 0, stream>>>(h, xn);
    mgemm8<0><<<dim3(16, 33), 512, 0, stream>>>(xn, wq, nullptr, act, MROWS, 4096, DD);
    attn_kernel<<<dim3(9, HH, BB), 256, 0, stream>>>(act, biasT, av);
    uln_kernel<<<MROWS, 256, 0, stream>>>(av, act, xn);
    mgemm1<<<dim3(8, 65), 256, 0, stream>>>(xn, wo, outB + l * DD, h, MROWS, DD, DD);
    rms_kernel<<<MROWS, 256, 0, stream>>>(h, xn);
    mgemm8<3><<<dim3(16, 33), 512, 0, stream>>>(xn, wf1, fc1B + (size_t)l * 4096, gated, MROWS, 2048, DD);
    mgemm1<<<dim3(8, 65), 256, 0, stream>>>(gated, wf2, fc2B + l * DD, h, MROWS, DD, 2048);
  }
}

// Round 18
// 1064.687 us; speedup vs baseline: 1.0113x; 1.0113x over previous
//
#include <hip/hip_runtime.h>
#include <hip/hip_bf16.h>
#include <math.h>

#define BB 8
#define SEQN 1025
#define DD 1024
#define HH 8
#define HD 128
#define LL 2
#define MROWS (BB*SEQN)     // 8200
#define NBUCKET 64

using short8 = __attribute__((ext_vector_type(8))) short;
using f32x4  = __attribute__((ext_vector_type(4))) float;
using f32x16 = __attribute__((ext_vector_type(16))) float;

__device__ __forceinline__ float silu_f(float x) { return x / (1.f + expf(-x)); }

__device__ __forceinline__ float bf2f(ushort u) {
  union { uint i; float f; } x; x.i = ((uint)u) << 16; return x.f;
}
__device__ __forceinline__ ushort f2bf(float f) {
  __hip_bfloat16 b = __float2bfloat16(f);
  return *reinterpret_cast<ushort*>(&b);
}
__device__ __forceinline__ void gll16(const void* g, void* l) {
  __builtin_amdgcn_global_load_lds((const __attribute__((address_space(1))) void*)g,
                                   (__attribute__((address_space(3))) void*)l, 16, 0, 0);
}
__device__ __forceinline__ uint pkbf(float lo, float hi) {
  uint r;
  asm("v_cvt_pk_bf16_f32 %0, %1, %2" : "=v"(r) : "v"(lo), "v"(hi));
  return r;
}
__device__ __forceinline__ f32x16 z16() {
  f32x16 v;
#pragma unroll
  for (int i = 0; i < 16; ++i) v[i] = 0.f;
  return v;
}

// ---------------- weight transpose+convert: W[K,N] f32 -> Wt[N,K] bf16 ----------------
__global__ __launch_bounds__(256) void wtrans(const float* __restrict__ W,
                                              ushort* __restrict__ Wt, int K, int N) {
  __shared__ float tile[32][33];
  int tid = threadIdx.x;
  int tx = tid & 31, ty = tid >> 5;           // 32 x 8
  int n0 = blockIdx.x * 32, k0 = blockIdx.y * 32;
#pragma unroll
  for (int r = 0; r < 32; r += 8)
    tile[ty + r][tx] = W[(size_t)(k0 + ty + r) * N + n0 + tx];
  __syncthreads();
#pragma unroll
  for (int r = 0; r < 32; r += 8)
    Wt[(size_t)(n0 + ty + r) * K + k0 + tx] = f2bf(tile[tx][ty + r]);
}

// ---------------- rel-attn bias, TRANSPOSED + bf16: biasT[b][j][i] ----------------
__global__ __launch_bounds__(256) void bias_kernel(const int* __restrict__ ts,
    const float* __restrict__ ts_w, const float* __restrict__ pos_w,
    ushort* __restrict__ biasT)
{
  int i = blockIdx.x * 256 + threadIdx.x;
  int j = blockIdx.y;
  int b = blockIdx.z;
  if (i >= SEQN) return;
  int ip1 = i + 1; if (ip1 > SEQN - 1) ip1 = SEQN - 1;
  long long t1 = (long long)ts[b * SEQN + ip1];
  long long t0 = (long long)ts[b * SEQN + j];
  long long d = t1 - t0;
  if (d < 0) d = -d;
  if (d < 1) d = 1;
  int bucket = (int)(logf((float)d) / 0.301f);
  if (bucket < 0) bucket = 0;
  if (bucket > NBUCKET) bucket = NBUCKET;
  biasT[((size_t)(b * SEQN + j)) * SEQN + i] = f2bf(pos_w[j - i + SEQN - 1] + ts_w[bucket]);
}

// ============ norm family: wave-per-row, 4 rows/block, no barriers (R18) ============
// Each 256-thread block = 4 waves; wave w owns row blockIdx.x*4 + w; lane owns
// 16 elems in 4 coalesced float4 passes. Reduction = 64-lane shuffle only.

__global__ __launch_bounds__(256) void lnh_kernel(const float* __restrict__ in,
    float* __restrict__ hout, ushort* __restrict__ out) {
  const int row = blockIdx.x * 4 + (threadIdx.x >> 6);
  const int lane = threadIdx.x & 63;
  const float* x = in + (size_t)row * DD;
  float4 v[4];
  float s = 0.f, ss = 0.f;
#pragma unroll
  for (int i = 0; i < 4; ++i) {
    v[i] = *(const float4*)&x[(lane + i * 64) * 4];
    s  += v[i].x + v[i].y + v[i].z + v[i].w;
    ss += v[i].x*v[i].x + v[i].y*v[i].y + v[i].z*v[i].z + v[i].w*v[i].w;
  }
#pragma unroll
  for (int off = 32; off >= 1; off >>= 1) { s += __shfl_xor(s, off); ss += __shfl_xor(ss, off); }
  float mu = s * (1.f / DD);
  float var = fmaxf(ss * (1.f / DD) - mu * mu, 0.f);
  float inv = 1.f / sqrtf(var + 1e-8f);
#pragma unroll
  for (int i = 0; i < 4; ++i) {
    *(float4*)&hout[(size_t)row * DD + (lane + i * 64) * 4] = v[i];
    ushort4 o;
    o.x = f2bf((v[i].x - mu) * inv); o.y = f2bf((v[i].y - mu) * inv);
    o.z = f2bf((v[i].z - mu) * inv); o.w = f2bf((v[i].w - mu) * inv);
    *(ushort4*)&out[(size_t)row * DD + (lane + i * 64) * 4] = o;
  }
}

__global__ __launch_bounds__(256) void ln_kernel(const float* __restrict__ in,
                                                 ushort* __restrict__ out) {
  const int row = blockIdx.x * 4 + (threadIdx.x >> 6);
  const int lane = threadIdx.x & 63;
  const float* x = in + (size_t)row * DD;
  float4 v[4];
  float s = 0.f, ss = 0.f;
#pragma unroll
  for (int i = 0; i < 4; ++i) {
    v[i] = *(const float4*)&x[(lane + i * 64) * 4];
    s  += v[i].x + v[i].y + v[i].z + v[i].w;
    ss += v[i].x*v[i].x + v[i].y*v[i].y + v[i].z*v[i].z + v[i].w*v[i].w;
  }
#pragma unroll
  for (int off = 32; off >= 1; off >>= 1) { s += __shfl_xor(s, off); ss += __shfl_xor(ss, off); }
  float mu = s * (1.f / DD);
  float var = fmaxf(ss * (1.f / DD) - mu * mu, 0.f);
  float inv = 1.f / sqrtf(var + 1e-8f);
#pragma unroll
  for (int i = 0; i < 4; ++i) {
    ushort4 o;
    o.x = f2bf((v[i].x - mu) * inv); o.y = f2bf((v[i].y - mu) * inv);
    o.z = f2bf((v[i].z - mu) * inv); o.w = f2bf((v[i].w - mu) * inv);
    *(ushort4*)&out[(size_t)row * DD + (lane + i * 64) * 4] = o;
  }
}

__global__ __launch_bounds__(256) void rms_kernel(const float* __restrict__ in,
                                                  ushort* __restrict__ out) {
  const int row = blockIdx.x * 4 + (threadIdx.x >> 6);
  const int lane = threadIdx.x & 63;
  const float* x = in + (size_t)row * DD;
  float4 v[4];
  float ss = 0.f;
#pragma unroll
  for (int i = 0; i < 4; ++i) {
    v[i] = *(const float4*)&x[(lane + i * 64) * 4];
    ss += v[i].x*v[i].x + v[i].y*v[i].y + v[i].z*v[i].z + v[i].w*v[i].w;
  }
#pragma unroll
  for (int off = 32; off >= 1; off >>= 1) ss += __shfl_xor(ss, off);
  float inv = 1.f / sqrtf(ss * (1.f / DD) + 1e-8f);
#pragma unroll
  for (int i = 0; i < 4; ++i) {
    ushort4 o;
    o.x = f2bf(v[i].x * inv); o.y = f2bf(v[i].y * inv);
    o.z = f2bf(v[i].z * inv); o.w = f2bf(v[i].w * inv);
    *(ushort4*)&out[(size_t)row * DD + (lane + i * 64) * 4] = o;
  }
}

// out[d] = u[d] * layernorm(av)[d]   (av bf16, u bf16 from act, out bf16)
__global__ __launch_bounds__(256) void uln_kernel(const ushort* __restrict__ av,
    const ushort* __restrict__ act, ushort* __restrict__ out) {
  const int row = blockIdx.x * 4 + (threadIdx.x >> 6);
  const int lane = threadIdx.x & 63;
  float4 v[4];
  float s = 0.f, ss = 0.f;
#pragma unroll
  for (int i = 0; i < 4; ++i) {
    ushort4 ub = *(const ushort4*)&av[(size_t)row * DD + (lane + i * 64) * 4];
    v[i].x = bf2f(ub.x); v[i].y = bf2f(ub.y); v[i].z = bf2f(ub.z); v[i].w = bf2f(ub.w);
    s  += v[i].x + v[i].y + v[i].z + v[i].w;
    ss += v[i].x*v[i].x + v[i].y*v[i].y + v[i].z*v[i].z + v[i].w*v[i].w;
  }
#pragma unroll
  for (int off = 32; off >= 1; off >>= 1) { s += __shfl_xor(s, off); ss += __shfl_xor(ss, off); }
  float mu = s * (1.f / DD);
  float var = fmaxf(ss * (1.f / DD) - mu * mu, 0.f);
  float inv = 1.f / sqrtf(var + 1e-8f);
#pragma unroll
  for (int i = 0; i < 4; ++i) {
    ushort4 uu = *(const ushort4*)&act[(size_t)row * 4096 + 3072 + (lane + i * 64) * 4];
    ushort4 o;
    o.x = f2bf(bf2f(uu.x) * (v[i].x - mu) * inv);
    o.y = f2bf(bf2f(uu.y) * (v[i].y - mu) * inv);
    o.z = f2bf(bf2f(uu.z) * (v[i].z - mu) * inv);
    o.w = f2bf(bf2f(uu.w) * (v[i].w - mu) * inv);
    *(ushort4*)&out[(size_t)row * DD + (lane + i * 64) * 4] = o;
  }
}

// ---------------- bf16 MFMA GEMM (BK=32, 3-buffer depth-2 pipeline), 256 thr ----
// N=1024 MODE1 GEMMs (out-proj, fc2): f32 out += AW + bvec.
__global__ __launch_bounds__(256) void mgemm1(const ushort* __restrict__ A,
    const ushort* __restrict__ Bt, const float* __restrict__ bvec,
    float* __restrict__ Cout, int M, int Nn, int K)
{
  __shared__ ushort As[3][4096];
  __shared__ ushort Bs[3][4096];
  const int tid  = threadIdx.x;
  const int lane = tid & 63, wave = tid >> 6;
  const int wm = wave >> 1, wn = wave & 1;
  const int lrow = lane & 15, lk = lane >> 4;
  const int bm = blockIdx.y * 128, bn = blockIdx.x * 128;

  const ushort* Aga[2]; const ushort* Bga[2];
  ushort* Ada[2]; ushort* Bda[2];
#pragma unroll
  for (int i = 0; i < 2; ++i) {
    int c = tid + 256 * i;
    int row = c >> 2, s = c & 3;
    int sc = s ^ ((row >> 1) & 3);
    Aga[i] = A  + (size_t)(bm + row) * K + sc * 8;
    Bga[i] = Bt + (size_t)(bn + row) * K + sc * 8;
    Ada[i] = &As[0][c * 8];
    Bda[i] = &Bs[0][c * 8];
  }

  int aoff[4], boff[4];
#pragma unroll
  for (int m = 0; m < 4; ++m)
    aoff[m] = (wm * 64 + m * 16 + lrow) * 32 + ((lk ^ ((lrow >> 1) & 3)) * 8);
#pragma unroll
  for (int n = 0; n < 4; ++n)
    boff[n] = (wn * 64 + n * 16 + lrow) * 32 + ((lk ^ ((lrow >> 1) & 3)) * 8);

  f32x4 acc[4][4];
#pragma unroll
  for (int m = 0; m < 4; ++m)
#pragma unroll
    for (int n = 0; n < 4; ++n) acc[m][n] = (f32x4){0.f, 0.f, 0.f, 0.f};

  const int nk = K >> 5;
#pragma unroll
  for (int t = 0; t < 2; ++t) {
#pragma unroll
    for (int i = 0; i < 2; ++i) {
      gll16(Aga[i] + (t << 5), Ada[i] + t * 4096);
      gll16(Bga[i] + (t << 5), Bda[i] + t * 4096);
    }
  }
  int cur = 0, nxt2 = 2;
  for (int kt = 0; kt < nk; ++kt) {
    if (kt + 1 < nk) {
      asm volatile("s_waitcnt vmcnt(4)" ::: "memory");
    } else {
      asm volatile("s_waitcnt vmcnt(0)" ::: "memory");
    }
    __builtin_amdgcn_s_barrier();
    __builtin_amdgcn_sched_barrier(0);
    if (kt + 2 < nk) {
      const int ko = (kt + 2) << 5;
      const int bo = nxt2 * 4096;
#pragma unroll
      for (int i = 0; i < 2; ++i) {
        gll16(Aga[i] + ko, Ada[i] + bo);
        gll16(Bga[i] + ko, Bda[i] + bo);
      }
    }
    __builtin_amdgcn_s_setprio(1);
    {
      short8 af[4], bfr[4];
      const int co = cur * 4096;
#pragma unroll
      for (int m = 0; m < 4; ++m) af[m]  = *(const short8*)&As[0][co + aoff[m]];
#pragma unroll
      for (int n = 0; n < 4; ++n) bfr[n] = *(const short8*)&Bs[0][co + boff[n]];
#pragma unroll
      for (int m = 0; m < 4; ++m)
#pragma unroll
        for (int n = 0; n < 4; ++n)
          acc[m][n] = __builtin_amdgcn_mfma_f32_16x16x32_bf16(af[m], bfr[n], acc[m][n], 0, 0, 0);
    }
    __builtin_amdgcn_s_setprio(0);
    __builtin_amdgcn_sched_barrier(0);
    cur = (cur == 2) ? 0 : cur + 1;
    nxt2 = (nxt2 == 2) ? 0 : nxt2 + 1;
  }

  const int colbase = bn + wn * 64 + lrow;
  const int rowbase = bm + wm * 64 + lk * 4;
#pragma unroll
  for (int m = 0; m < 4; ++m) {
    int row0 = rowbase + m * 16;
#pragma unroll
    for (int n = 0; n < 4; ++n) {
      int col = colbase + n * 16;
      float bv = bvec[col];
#pragma unroll
      for (int r = 0; r < 4; ++r) {
        int row = row0 + r;
        if (row < M) {
          float* p = Cout + (size_t)row * Nn + col;
          *p += acc[m][n][r] + bv;
        }
      }
    }
  }
}

// ------- 8-phase wide bf16 MFMA GEMM: 256x256, BK=64, 8 waves, counted vmcnt -------
template<int MODE>
__global__ __launch_bounds__(512, 2) void mgemm8(const ushort* __restrict__ A,
    const ushort* __restrict__ Bt, const float* __restrict__ bvec,
    void* __restrict__ Cout, int M, int Nn, int K)
{
  __shared__ ushort LS[65536];   // 128 KB
  const int tid = threadIdx.x;
  const int lane = tid & 63, wave = tid >> 6;
  const int wm = wave >> 2, wn = wave & 3;       // 2m x 4n; wave tile 128x64
  const int lrow = lane & 15, lk = lane >> 4;
  const int bm = blockIdx.y * 256;

  const ushort* srcA[2]; const ushort* srcB[2];
  int ldsA[2], ldsB[2];
#pragma unroll
  for (int i = 0; i < 2; ++i) {
    int c = tid + 512 * i, row = c >> 2, s = c & 3;
    int sw = (s ^ ((row >> 1) & 3)) * 8;
    srcA[i] = A + (size_t)(bm + row) * K + sw;
    ldsA[i] = c * 8;
    int gr;
    if (MODE == 3) {
      gr = blockIdx.x * 128 + (row >> 5) * 16 + ((row >> 4) & 1) * 2048 + (row & 15);
    } else {
      gr = blockIdx.x * 256 + row;
    }
    srcB[i] = Bt + (size_t)gr * K + sw;
    ldsB[i] = c * 8;
  }
  int aoff[8], boff[4];
#pragma unroll
  for (int m = 0; m < 8; ++m)
    aoff[m] = (wm * 128 + m * 16 + lrow) * 32 + ((lk ^ ((lrow >> 1) & 3)) * 8);
#pragma unroll
  for (int n = 0; n < 4; ++n)
    boff[n] = (wn * 64 + n * 16 + lrow) * 32 + ((lk ^ ((lrow >> 1) & 3)) * 8);

  f32x4 acc[8][4];
#pragma unroll
  for (int m = 0; m < 8; ++m)
#pragma unroll
    for (int n = 0; n < 4; ++n) acc[m][n] = (f32x4){0.f, 0.f, 0.f, 0.f};

  const int NT = K >> 6;   // 16

#define STG_A(T, H, B)                                                        \
  { _Pragma("unroll")                                                         \
    for (int i = 0; i < 2; ++i)                                               \
      gll16(srcA[i] + ((T) << 6) + ((H) << 5),                                \
            (void*)&LS[((B) * 2 + (H)) * 8192 + ldsA[i]]); }
#define STG_B(T, H, B)                                                        \
  { _Pragma("unroll")                                                         \
    for (int i = 0; i < 2; ++i)                                               \
      gll16(srcB[i] + ((T) << 6) + ((H) << 5),                                \
            (void*)&LS[32768 + ((B) * 2 + (H)) * 8192 + ldsB[i]]); }

#define TILE4(T, B)                                                           \
  {                                                                           \
    const int t_ = (T);                                                       \
    { int ts = (t_ + 1 < NT) ? t_ + 1 : NT - 1; STG_A(ts, 1, (B) ^ 1); }      \
    asm volatile("s_waitcnt vmcnt(10)" ::: "memory");                         \
    __builtin_amdgcn_s_barrier();                                             \
    short8 bfr[4];                                                            \
    _Pragma("unroll")                                                         \
    for (int n = 0; n < 4; ++n)                                               \
      bfr[n] = *(const short8*)&LS[32768 + ((B) * 2 + 0) * 8192 + boff[n]];   \
    {                                                                         \
      short8 af[4];                                                           \
      _Pragma("unroll")                                                       \
      for (int mi = 0; mi < 4; ++mi)                                          \
        af[mi] = *(const short8*)&LS[((B) * 2 + 0) * 8192 + aoff[mi]];        \
      __builtin_amdgcn_s_setprio(1);                                          \
      _Pragma("unroll")                                                       \
      for (int mi = 0; mi < 4; ++mi)                                          \
        _Pragma("unroll")                                                     \
        for (int n = 0; n < 4; ++n)                                           \
          acc[mi][n] = __builtin_amdgcn_mfma_f32_16x16x32_bf16(af[mi], bfr[n], acc[mi][n], 0, 0, 0); \
      __builtin_amdgcn_s_setprio(0);                                          \
    }                                                                         \
    { int ts = (t_ + 1 < NT) ? t_ + 1 : NT - 1; STG_B(ts, 1, (B) ^ 1); }      \
    {                                                                         \
      short8 af[4];                                                           \
      _Pragma("unroll")                                                       \
      for (int mi = 0; mi < 4; ++mi)                                          \
        af[mi] = *(const short8*)&LS[((B) * 2 + 0) * 8192 + aoff[4 + mi]];    \
      __builtin_amdgcn_s_setprio(1);                                          \
      _Pragma("unroll")                                                       \
      for (int mi = 0; mi < 4; ++mi)                                          \
        _Pragma("unroll")                                                     \
        for (int n = 0; n < 4; ++n)                                           \
          acc[4 + mi][n] = __builtin_amdgcn_mfma_f32_16x16x32_bf16(af[mi], bfr[n], acc[4 + mi][n], 0, 0, 0); \
      __builtin_amdgcn_s_setprio(0);                                          \
    }                                                                         \
    __builtin_amdgcn_s_barrier();                                             \
    { int ts = (t_ + 2 < NT) ? t_ + 2 : NT - 1; STG_A(ts, 0, (B)); }          \
    asm volatile("s_waitcnt vmcnt(10)" ::: "memory");                         \
    __builtin_amdgcn_s_barrier();                                             \
    _Pragma("unroll")                                                         \
    for (int n = 0; n < 4; ++n)                                               \
      bfr[n] = *(const short8*)&LS[32768 + ((B) * 2 + 1) * 8192 + boff[n]];   \
    {                                                                         \
      short8 af[4];                                                           \
      _Pragma("unroll")                                                       \
      for (int mi = 0; mi < 4; ++mi)                                          \
        af[mi] = *(const short8*)&LS[((B) * 2 + 1) * 8192 + aoff[mi]];        \
      __builtin_amdgcn_s_setprio(1);                                          \
      _Pragma("unroll")                                                       \
      for (int mi = 0; mi < 4; ++mi)                                          \
        _Pragma("unroll")                                                     \
        for (int n = 0; n < 4; ++n)                                           \
          acc[mi][n] = __builtin_amdgcn_mfma_f32_16x16x32_bf16(af[mi], bfr[n], acc[mi][n], 0, 0, 0); \
      __builtin_amdgcn_s_setprio(0);                                          \
    }                                                                         \
    { int ts = (t_ + 2 < NT) ? t_ + 2 : NT - 1; STG_B(ts, 0, (B)); }          \
    {                                                                         \
      short8 af[4];                                                           \
      _Pragma("unroll")                                                       \
      for (int mi = 0; mi < 4; ++mi)                                          \
        af[mi] = *(const short8*)&LS[((B) * 2 + 1) * 8192 + aoff[4 + mi]];    \
      __builtin_amdgcn_s_setprio(1);                                          \
      _Pragma("unroll")                                                       \
      for (int mi = 0; mi < 4; ++mi)                                          \
        _Pragma("unroll")                                                     \
        for (int n = 0; n < 4; ++n)                                           \
          acc[4 + mi][n] = __builtin_amdgcn_mfma_f32_16x16x32_bf16(af[mi], bfr[n], acc[4 + mi][n], 0, 0, 0); \
      __builtin_amdgcn_s_setprio(0);                                          \
    }                                                                         \
    __builtin_amdgcn_s_barrier();                                             \
  }

  STG_A(0, 0, 0); STG_B(0, 0, 0); STG_A(0, 1, 0); STG_B(0, 1, 0);
  STG_A(1, 0, 1); STG_B(1, 0, 1);
  for (int tt = 0; tt < NT; tt += 2) {
    TILE4(tt, 0);
    TILE4(tt + 1, 1);
  }
#undef TILE4
#undef STG_A
#undef STG_B

  const int rowb0 = bm + wm * 128 + lk * 4;
  if (MODE == 0) {
    const int colb0 = blockIdx.x * 256 + wn * 64 + lrow;
    __hip_bfloat16* Cb = (__hip_bfloat16*)Cout;
#pragma unroll
    for (int m = 0; m < 8; ++m) {
      int row0 = rowb0 + m * 16;
#pragma unroll
      for (int n = 0; n < 4; ++n) {
        int col = colb0 + n * 16;
#pragma unroll
        for (int r = 0; r < 4; ++r) {
          int row = row0 + r;
          if (row < M)
            Cb[(size_t)row * Nn + col] = __float2bfloat16(silu_f(acc[m][n][r]));
        }
      }
    }
  } else {
    __hip_bfloat16* Cb = (__hip_bfloat16*)Cout;   // gated [M][2048]
#pragma unroll
    for (int q = 0; q < 2; ++q) {
      int vcol = blockIdx.x * 128 + (2 * wn + q) * 16 + lrow;
      float bvv = bvec[vcol];
      float bvg = bvec[vcol + 2048];
#pragma unroll
      for (int m = 0; m < 8; ++m) {
        int row0 = rowb0 + m * 16;
#pragma unroll
        for (int r = 0; r < 4; ++r) {
          int row = row0 + r;
          if (row < M) {
            float v = acc[m][2 * q][r] + bvv;
            float g = acc[m][2 * q + 1][r] + bvg;
            Cb[(size_t)row * 2048 + vcol] = __float2bfloat16(silu_f(g) * v);
          }
        }
      }
    }
  }
}

// ---------------- MFMA causal silu-attention (double-buffered K/V, 1 barrier/tile) --
__global__ __launch_bounds__(256) void attn_kernel(const ushort* __restrict__ act,
    const ushort* __restrict__ biasT, ushort* __restrict__ av)
{
  __shared__ __align__(16) char KL[16384];   // 2 bufs x [32 j][128 d] swizzled
  __shared__ __align__(16) char VL[16640];   // 2 bufs x subtiled V (8320 each)
  const int tid = threadIdx.x;
  const int l = tid & 63, w = tid >> 6;
  const int qi = (int)(gridDim.x - 1 - blockIdx.x);
  const int i0 = qi * 128;
  const int h = blockIdx.y, b = blockIdx.z;
  const int lo31 = l & 31, hi = l >> 5;

  const int jlim = (i0 + 128 < SEQN) ? i0 + 128 : SEQN;
  const int nt = (jlim + 31) >> 5;

  const int gi_q = i0 + w * 32 + lo31;
  const int gi_qc = gi_q < SEQN ? gi_q : SEQN - 1;
  const size_t actB = (size_t)b * SEQN;
  const ushort* qrow = act + (actB + gi_qc) * 4096 + h * HD;
  short8 qreg[8];
#pragma unroll
  for (int dc = 0; dc < 8; ++dc)
    qreg[dc] = *(const short8*)(qrow + dc * 16 + hi * 8);

  f32x16 acc[4];
#pragma unroll
  for (int dt = 0; dt < 4; ++dt) acc[dt] = z16();

  const int id0 = tid, id1 = tid + 256;
  const int j_0 = id0 >> 4, c8_0 = (id0 & 15) * 8;
  const int j_1 = id1 >> 4, c8_1 = (id1 & 15) * 8;
  char* kw0 = KL + j_0 * 256 + (((id0 & 15) ^ (j_0 & 15)) << 4);
  char* kw1 = KL + j_1 * 256 + (((id1 & 15) ^ (j_1 & 15)) << 4);
  char* vw0 = VL + ((id0 & 15) >> 1) * 1040 + j_0 * 32 + (id0 & 1) * 16;
  char* vw1 = VL + ((id1 & 15) >> 1) * 1040 + j_1 * 32 + (id1 & 1) * 16;
  const uint vbase0 = (uint)(size_t)(__attribute__((address_space(3))) char*)
      (VL + ((l >> 4) & 1) * 1040 + hi * 256 + (l & 15) * 8);

  short8 kr0, kr1, vr0, vr1;
  {
    const ushort* p0 = act + (actB + j_0) * 4096 + 1024 + h * HD + c8_0;
    const ushort* p1 = act + (actB + j_1) * 4096 + 1024 + h * HD + c8_1;
    kr0 = *(const short8*)p0; vr0 = *(const short8*)(p0 + 1024);
    kr1 = *(const short8*)p1; vr1 = *(const short8*)(p1 + 1024);
  }
  const float invN = 1.f / (float)SEQN;
  const int gi0w = i0 + w * 32;

  for (int t = 0; t < nt; ++t) {
    const int j0 = t * 32;
    const int kb = (t & 1) * 8192;
    const int vb = (t & 1) * 8320;
    *(short8*)(kw0 + kb) = kr0; *(short8*)(kw1 + kb) = kr1;
    *(short8*)(vw0 + vb) = vr0; *(short8*)(vw1 + vb) = vr1;
    __syncthreads();
    if (t + 1 < nt) {
      const ushort* p0 = act + (actB + j0 + 32 + j_0) * 4096 + 1024 + h * HD + c8_0;
      const ushort* p1 = act + (actB + j0 + 32 + j_1) * 4096 + 1024 + h * HD + c8_1;
      kr0 = *(const short8*)p0; vr0 = *(const short8*)(p0 + 1024);
      kr1 = *(const short8*)p1; vr1 = *(const short8*)(p1 + 1024);
    }
    if (j0 <= gi0w + 31 && gi0w < SEQN) {
      float bv[16];
#pragma unroll
      for (int r = 0; r < 16; ++r) {
        int j = (r & 3) + 8 * (r >> 2) + 4 * hi;
        int gj = j0 + j;
        int gjc = gj < SEQN ? gj : SEQN - 1;
        bv[r] = bf2f(biasT[(actB + gjc) * SEQN + gi_qc]);
      }
      f32x16 st = z16();
#pragma unroll
      for (int dc = 0; dc < 8; ++dc) {
        short8 kf = *(const short8*)(KL + kb + lo31 * 256 + ((((dc << 1) + hi) ^ (lo31 & 15)) << 4));
        st = __builtin_amdgcn_mfma_f32_32x32x16_bf16(kf, qreg[dc], st, 0, 0, 0);
      }
      float p[16];
#pragma unroll
      for (int r = 0; r < 16; ++r) {
        int j = (r & 3) + 8 * (r >> 2) + 4 * hi;
        int gj = j0 + j;
        float s = st[r] + bv[r];
        float pw = s * __builtin_amdgcn_rcpf(1.f + __expf(-s)) * invN;
        p[r] = ((gj <= gi_q) && (gi_q < SEQN)) ? pw : 0.f;
      }
      short8 paf[2];
#pragma unroll
      for (int g = 0; g < 2; ++g) {
        uint w0 = pkbf(p[g * 8 + 0], p[g * 8 + 1]);
        uint w2 = pkbf(p[g * 8 + 4], p[g * 8 + 5]);
        uint w1 = pkbf(p[g * 8 + 2], p[g * 8 + 3]);
        uint w3 = pkbf(p[g * 8 + 6], p[g * 8 + 7]);
        asm volatile("v_permlane32_swap_b32 %0, %1" : "+v"(w0), "+v"(w2));
        asm volatile("v_permlane32_swap_b32 %0, %1" : "+v"(w1), "+v"(w3));
        union UF { uint u[4]; short8 s; } uf;
        uf.u[0] = w0; uf.u[1] = w1; uf.u[2] = w2; uf.u[3] = w3;
        paf[g] = uf.s;
      }
      const uint vbase = vbase0 + vb;
      uint64_t v00, v01, v02, v03, v10, v11, v12, v13, v20, v21, v22, v23, v30, v31, v32, v33;
      asm volatile(
        "ds_read_b64_tr_b16 %0, %16 offset:0\n\t"
        "ds_read_b64_tr_b16 %1, %16 offset:128\n\t"
        "ds_read_b64_tr_b16 %2, %16 offset:512\n\t"
        "ds_read_b64_tr_b16 %3, %16 offset:640\n\t"
        "ds_read_b64_tr_b16 %4, %16 offset:2080\n\t"
        "ds_read_b64_tr_b16 %5, %16 offset:2208\n\t"
        "ds_read_b64_tr_b16 %6, %16 offset:2592\n\t"
        "ds_read_b64_tr_b16 %7, %16 offset:2720\n\t"
        "ds_read_b64_tr_b16 %8, %16 offset:4160\n\t"
        "ds_read_b64_tr_b16 %9, %16 offset:4288\n\t"
        "ds_read_b64_tr_b16 %10, %16 offset:4672\n\t"
        "ds_read_b64_tr_b16 %11, %16 offset:4800\n\t"
        "ds_read_b64_tr_b16 %12, %16 offset:6240\n\t"
        "ds_read_b64_tr_b16 %13, %16 offset:6368\n\t"
        "ds_read_b64_tr_b16 %14, %16 offset:6752\n\t"
        "ds_read_b64_tr_b16 %15, %16 offset:6880\n\t"
        "s_waitcnt lgkmcnt(0)"
        : "=v"(v00), "=v"(v01), "=v"(v02), "=v"(v03),
          "=v"(v10), "=v"(v11), "=v"(v12), "=v"(v13),
          "=v"(v20), "=v"(v21), "=v"(v22), "=v"(v23),
          "=v"(v30), "=v"(v31), "=v"(v32), "=v"(v33)
        : "v"(vbase) : "memory");
      union UV { uint64_t q[2]; short8 s; };
      { UV uv; uv.q[0] = v00; uv.q[1] = v01;
        acc[0] = __builtin_amdgcn_mfma_f32_32x32x16_bf16(paf[0], uv.s, acc[0], 0, 0, 0); }
      { UV uv; uv.q[0] = v02; uv.q[1] = v03;
        acc[0] = __builtin_amdgcn_mfma_f32_32x32x16_bf16(paf[1], uv.s, acc[0], 0, 0, 0); }
      { UV uv; uv.q[0] = v10; uv.q[1] = v11;
        acc[1] = __builtin_amdgcn_mfma_f32_32x32x16_bf16(paf[0], uv.s, acc[1], 0, 0, 0); }
      { UV uv; uv.q[0] = v12; uv.q[1] = v13;
        acc[1] = __builtin_amdgcn_mfma_f32_32x32x16_bf16(paf[1], uv.s, acc[1], 0, 0, 0); }
      { UV uv; uv.q[0] = v20; uv.q[1] = v21;
        acc[2] = __builtin_amdgcn_mfma_f32_32x32x16_bf16(paf[0], uv.s, acc[2], 0, 0, 0); }
      { UV uv; uv.q[0] = v22; uv.q[1] = v23;
        acc[2] = __builtin_amdgcn_mfma_f32_32x32x16_bf16(paf[1], uv.s, acc[2], 0, 0, 0); }
      { UV uv; uv.q[0] = v30; uv.q[1] = v31;
        acc[3] = __builtin_amdgcn_mfma_f32_32x32x16_bf16(paf[0], uv.s, acc[3], 0, 0, 0); }
      { UV uv; uv.q[0] = v32; uv.q[1] = v33;
        acc[3] = __builtin_amdgcn_mfma_f32_32x32x16_bf16(paf[1], uv.s, acc[3], 0, 0, 0); }
    }
  }
#pragma unroll
  for (int dt = 0; dt < 4; ++dt) {
#pragma unroll
    for (int r = 0; r < 16; ++r) {
      int q = (r & 3) + 8 * (r >> 2) + 4 * hi;
      int gi = i0 + w * 32 + q;
      if (gi < SEQN)
        av[(actB + gi) * DD + h * HD + dt * 32 + lo31] = f2bf(acc[dt][r]);
    }
  }
}

// ---------------- launch ----------------
extern "C" void kernel_launch(void* const* d_in, const int* in_sizes, int n_in,
                              void* d_out, int out_size, void* d_ws, size_t ws_size,
                              hipStream_t stream) {
  const float* seqs  = (const float*)d_in[0];
  const int*   ts    = (const int*)d_in[2];
  const float* qkvuW = (const float*)d_in[3];
  const float* outW  = (const float*)d_in[4];
  const float* outB  = (const float*)d_in[5];
  const float* tsW   = (const float*)d_in[6];
  const float* posW  = (const float*)d_in[7];
  const float* fc1W  = (const float*)d_in[8];
  const float* fc1B  = (const float*)d_in[9];
  const float* fc2W  = (const float*)d_in[10];
  const float* fc2B  = (const float*)d_in[11];
  float* h = (float*)d_out;
  char* ws = (char*)d_ws;

  ushort* xn    = (ushort*)(ws);                 // 8448*1024*2  = 17,301,504
  ushort* act   = (ushort*)(ws + 17301504);      // 8200*4096*2  = 67,174,400
  ushort* gated = (ushort*)(ws + 84475904);      // 8320*2048*2  = 34,078,720
  ushort* biasT = (ushort*)(ws + 118554624);     // 8*1025*1025*2= 16,810,000
  ushort* av    = (ushort*)(ws + 152174624);     // 8200*1024*2  = 16,793,600
  ushort* wq    = (ushort*)(ws + 185761824);     // 4096*1024*2
  ushort* wo    = (ushort*)(ws + 194150432);     // 1024*1024*2
  ushort* wf1   = (ushort*)(ws + 196247584);     // 4096*1024*2
  ushort* wf2   = (ushort*)(ws + 204636192);     // 1024*2048*2  (end 208,830,496)

  for (int l = 0; l < LL; l++) {
    wtrans<<<dim3(128, 32), 256, 0, stream>>>(qkvuW + (size_t)l * DD * 4096, wq, DD, 4096);
    wtrans<<<dim3(32, 32),  256, 0, stream>>>(outW  + (size_t)l * DD * DD,   wo, DD, DD);
    wtrans<<<dim3(128, 32), 256, 0, stream>>>(fc1W  + (size_t)l * DD * 4096, wf1, DD, 4096);
    wtrans<<<dim3(32, 64),  256, 0, stream>>>(fc2W  + (size_t)l * 2048 * DD, wf2, 2048, DD);

    bias_kernel<<<dim3(5, SEQN, BB), 256, 0, stream>>>(
        ts, tsW + l * (NBUCKET + 1), posW + l * (2 * SEQN - 1), biasT);

    if (l == 0)
      lnh_kernel<<<MROWS / 4, 256, 0, stream>>>(seqs, h, xn);   // h = seqs; xn = LN(seqs)
    else
      ln_kernel<<<MROWS / 4, 256, 0, stream>>>(h, xn);
    mgemm8<0><<<dim3(16, 33), 512, 0, stream>>>(xn, wq, nullptr, act, MROWS, 4096, DD);
    attn_kernel<<<dim3(9, HH, BB), 256, 0, stream>>>(act, biasT, av);
    uln_kernel<<<MROWS / 4, 256, 0, stream>>>(av, act, xn);
    mgemm1<<<dim3(8, 65), 256, 0, stream>>>(xn, wo, outB + l * DD, h, MROWS, DD, DD);
    rms_kernel<<<MROWS / 4, 256, 0, stream>>>(h, xn);
    mgemm8<3><<<dim3(16, 33), 512, 0, stream>>>(xn, wf1, fc1B + (size_t)l * 4096, gated, MROWS, 2048, DD);
    mgemm1<<<dim3(8, 65), 256, 0, stream>>>(gated, wf2, fc2B + l * DD, h, MROWS, DD, 2048);
  }
}

// Round 19
// 1039.644 us; speedup vs baseline: 1.0357x; 1.0241x over previous
//
#include <hip/hip_runtime.h>
#include <hip/hip_bf16.h>
#include <math.h>

#define BB 8
#define SEQN 1025
#define DD 1024
#define HH 8
#define HD 128
#define LL 2
#define MROWS (BB*SEQN)     // 8200
#define NBUCKET 64

using short8 = __attribute__((ext_vector_type(8))) short;
using f32x4  = __attribute__((ext_vector_type(4))) float;
using f32x16 = __attribute__((ext_vector_type(16))) float;

__device__ __forceinline__ float silu_f(float x) { return x / (1.f + expf(-x)); }

__device__ __forceinline__ float bf2f(ushort u) {
  union { uint i; float f; } x; x.i = ((uint)u) << 16; return x.f;
}
__device__ __forceinline__ ushort f2bf(float f) {
  __hip_bfloat16 b = __float2bfloat16(f);
  return *reinterpret_cast<ushort*>(&b);
}
__device__ __forceinline__ void gll16(const void* g, void* l) {
  __builtin_amdgcn_global_load_lds((const __attribute__((address_space(1))) void*)g,
                                   (__attribute__((address_space(3))) void*)l, 16, 0, 0);
}
__device__ __forceinline__ uint pkbf(float lo, float hi) {
  uint r;
  asm("v_cvt_pk_bf16_f32 %0, %1, %2" : "=v"(r) : "v"(lo), "v"(hi));
  return r;
}
__device__ __forceinline__ f32x16 z16() {
  f32x16 v;
#pragma unroll
  for (int i = 0; i < 16; ++i) v[i] = 0.f;
  return v;
}

// ======== fused per-layer prep: 4 weight transposes + bias table, ONE dispatch ======
// Segments (flat grid, block-uniform branch):
//   [0,4096)        wq  : qkvuW (K=1024,N=4096) -> wq[N][K]
//   [4096,8192)     wf1 : fc1W  (K=1024,N=4096) -> wf1
//   [8192,10240)    wf2 : fc2W  (K=2048,N=1024) -> wf2
//   [10240,11264)   wo  : outW  (K=1024,N=1024) -> wo
//   [11264,52264)   bias: biasT[b][j][i] bf16 (41000 blocks of 256 threads)
__device__ __forceinline__ void wtrans_blk(const float* __restrict__ W,
    ushort* __restrict__ Wt, int K, int N, int bx, int by, int tid,
    float tile[32][33]) {
  const int tx = tid & 31, ty = tid >> 5;           // 32 x 8
  const int n0 = bx * 32, k0 = by * 32;
#pragma unroll
  for (int r = 0; r < 32; r += 8)
    tile[ty + r][tx] = W[(size_t)(k0 + ty + r) * N + n0 + tx];
  __syncthreads();
#pragma unroll
  for (int r = 0; r < 32; r += 8)
    Wt[(size_t)(n0 + ty + r) * K + k0 + tx] = f2bf(tile[tx][ty + r]);
}

__global__ __launch_bounds__(256) void prep_kernel(
    const float* __restrict__ qkvuW, const float* __restrict__ outW,
    const float* __restrict__ fc1W,  const float* __restrict__ fc2W,
    ushort* __restrict__ wq, ushort* __restrict__ wo,
    ushort* __restrict__ wf1, ushort* __restrict__ wf2,
    const int* __restrict__ ts, const float* __restrict__ ts_w,
    const float* __restrict__ pos_w, ushort* __restrict__ biasT)
{
  __shared__ float tile[32][33];
  const int bid = blockIdx.x;
  const int tid = threadIdx.x;
  if (bid < 4096) {
    wtrans_blk(qkvuW, wq, 1024, 4096, bid & 127, bid >> 7, tid, tile);
  } else if (bid < 8192) {
    const int b2 = bid - 4096;
    wtrans_blk(fc1W, wf1, 1024, 4096, b2 & 127, b2 >> 7, tid, tile);
  } else if (bid < 10240) {
    const int b3 = bid - 8192;
    wtrans_blk(fc2W, wf2, 2048, 1024, b3 & 31, b3 >> 5, tid, tile);
  } else if (bid < 11264) {
    const int b4 = bid - 10240;
    wtrans_blk(outW, wo, 1024, 1024, b4 & 31, b4 >> 5, tid, tile);
  } else {
    const int b5 = bid - 11264;                  // [0, 41000)
    const int b  = b5 / 5125;
    const int rem = b5 % 5125;
    const int j  = rem / 5;
    const int i  = (rem % 5) * 256 + tid;
    if (i >= SEQN) return;
    int ip1 = i + 1; if (ip1 > SEQN - 1) ip1 = SEQN - 1;
    long long t1 = (long long)ts[b * SEQN + ip1];
    long long t0 = (long long)ts[b * SEQN + j];
    long long d = t1 - t0;
    if (d < 0) d = -d;
    if (d < 1) d = 1;
    int bucket = (int)(logf((float)d) / 0.301f);
    if (bucket < 0) bucket = 0;
    if (bucket > NBUCKET) bucket = NBUCKET;
    biasT[((size_t)(b * SEQN + j)) * SEQN + i] = f2bf(pos_w[j - i + SEQN - 1] + ts_w[bucket]);
  }
}

// ============ norm family: wave-per-row, 4 rows/block, no barriers ============
__global__ __launch_bounds__(256) void lnh_kernel(const float* __restrict__ in,
    float* __restrict__ hout, ushort* __restrict__ out) {
  const int row = blockIdx.x * 4 + (threadIdx.x >> 6);
  const int lane = threadIdx.x & 63;
  const float* x = in + (size_t)row * DD;
  float4 v[4];
  float s = 0.f, ss = 0.f;
#pragma unroll
  for (int i = 0; i < 4; ++i) {
    v[i] = *(const float4*)&x[(lane + i * 64) * 4];
    s  += v[i].x + v[i].y + v[i].z + v[i].w;
    ss += v[i].x*v[i].x + v[i].y*v[i].y + v[i].z*v[i].z + v[i].w*v[i].w;
  }
#pragma unroll
  for (int off = 32; off >= 1; off >>= 1) { s += __shfl_xor(s, off); ss += __shfl_xor(ss, off); }
  float mu = s * (1.f / DD);
  float var = fmaxf(ss * (1.f / DD) - mu * mu, 0.f);
  float inv = 1.f / sqrtf(var + 1e-8f);
#pragma unroll
  for (int i = 0; i < 4; ++i) {
    *(float4*)&hout[(size_t)row * DD + (lane + i * 64) * 4] = v[i];
    ushort4 o;
    o.x = f2bf((v[i].x - mu) * inv); o.y = f2bf((v[i].y - mu) * inv);
    o.z = f2bf((v[i].z - mu) * inv); o.w = f2bf((v[i].w - mu) * inv);
    *(ushort4*)&out[(size_t)row * DD + (lane + i * 64) * 4] = o;
  }
}

__global__ __launch_bounds__(256) void ln_kernel(const float* __restrict__ in,
                                                 ushort* __restrict__ out) {
  const int row = blockIdx.x * 4 + (threadIdx.x >> 6);
  const int lane = threadIdx.x & 63;
  const float* x = in + (size_t)row * DD;
  float4 v[4];
  float s = 0.f, ss = 0.f;
#pragma unroll
  for (int i = 0; i < 4; ++i) {
    v[i] = *(const float4*)&x[(lane + i * 64) * 4];
    s  += v[i].x + v[i].y + v[i].z + v[i].w;
    ss += v[i].x*v[i].x + v[i].y*v[i].y + v[i].z*v[i].z + v[i].w*v[i].w;
  }
#pragma unroll
  for (int off = 32; off >= 1; off >>= 1) { s += __shfl_xor(s, off); ss += __shfl_xor(ss, off); }
  float mu = s * (1.f / DD);
  float var = fmaxf(ss * (1.f / DD) - mu * mu, 0.f);
  float inv = 1.f / sqrtf(var + 1e-8f);
#pragma unroll
  for (int i = 0; i < 4; ++i) {
    ushort4 o;
    o.x = f2bf((v[i].x - mu) * inv); o.y = f2bf((v[i].y - mu) * inv);
    o.z = f2bf((v[i].z - mu) * inv); o.w = f2bf((v[i].w - mu) * inv);
    *(ushort4*)&out[(size_t)row * DD + (lane + i * 64) * 4] = o;
  }
}

__global__ __launch_bounds__(256) void rms_kernel(const float* __restrict__ in,
                                                  ushort* __restrict__ out) {
  const int row = blockIdx.x * 4 + (threadIdx.x >> 6);
  const int lane = threadIdx.x & 63;
  const float* x = in + (size_t)row * DD;
  float4 v[4];
  float ss = 0.f;
#pragma unroll
  for (int i = 0; i < 4; ++i) {
    v[i] = *(const float4*)&x[(lane + i * 64) * 4];
    ss += v[i].x*v[i].x + v[i].y*v[i].y + v[i].z*v[i].z + v[i].w*v[i].w;
  }
#pragma unroll
  for (int off = 32; off >= 1; off >>= 1) ss += __shfl_xor(ss, off);
  float inv = 1.f / sqrtf(ss * (1.f / DD) + 1e-8f);
#pragma unroll
  for (int i = 0; i < 4; ++i) {
    ushort4 o;
    o.x = f2bf(v[i].x * inv); o.y = f2bf(v[i].y * inv);
    o.z = f2bf(v[i].z * inv); o.w = f2bf(v[i].w * inv);
    *(ushort4*)&out[(size_t)row * DD + (lane + i * 64) * 4] = o;
  }
}

__global__ __launch_bounds__(256) void uln_kernel(const ushort* __restrict__ av,
    const ushort* __restrict__ act, ushort* __restrict__ out) {
  const int row = blockIdx.x * 4 + (threadIdx.x >> 6);
  const int lane = threadIdx.x & 63;
  float4 v[4];
  float s = 0.f, ss = 0.f;
#pragma unroll
  for (int i = 0; i < 4; ++i) {
    ushort4 ub = *(const ushort4*)&av[(size_t)row * DD + (lane + i * 64) * 4];
    v[i].x = bf2f(ub.x); v[i].y = bf2f(ub.y); v[i].z = bf2f(ub.z); v[i].w = bf2f(ub.w);
    s  += v[i].x + v[i].y + v[i].z + v[i].w;
    ss += v[i].x*v[i].x + v[i].y*v[i].y + v[i].z*v[i].z + v[i].w*v[i].w;
  }
#pragma unroll
  for (int off = 32; off >= 1; off >>= 1) { s += __shfl_xor(s, off); ss += __shfl_xor(ss, off); }
  float mu = s * (1.f / DD);
  float var = fmaxf(ss * (1.f / DD) - mu * mu, 0.f);
  float inv = 1.f / sqrtf(var + 1e-8f);
#pragma unroll
  for (int i = 0; i < 4; ++i) {
    ushort4 uu = *(const ushort4*)&act[(size_t)row * 4096 + 3072 + (lane + i * 64) * 4];
    ushort4 o;
    o.x = f2bf(bf2f(uu.x) * (v[i].x - mu) * inv);
    o.y = f2bf(bf2f(uu.y) * (v[i].y - mu) * inv);
    o.z = f2bf(bf2f(uu.z) * (v[i].z - mu) * inv);
    o.w = f2bf(bf2f(uu.w) * (v[i].w - mu) * inv);
    *(ushort4*)&out[(size_t)row * DD + (lane + i * 64) * 4] = o;
  }
}

// ---------------- bf16 MFMA GEMM (BK=32, 3-buffer depth-2 pipeline), 256 thr ----
__global__ __launch_bounds__(256) void mgemm1(const ushort* __restrict__ A,
    const ushort* __restrict__ Bt, const float* __restrict__ bvec,
    float* __restrict__ Cout, int M, int Nn, int K)
{
  __shared__ ushort As[3][4096];
  __shared__ ushort Bs[3][4096];
  const int tid  = threadIdx.x;
  const int lane = tid & 63, wave = tid >> 6;
  const int wm = wave >> 1, wn = wave & 1;
  const int lrow = lane & 15, lk = lane >> 4;
  const int bm = blockIdx.y * 128, bn = blockIdx.x * 128;

  const ushort* Aga[2]; const ushort* Bga[2];
  ushort* Ada[2]; ushort* Bda[2];
#pragma unroll
  for (int i = 0; i < 2; ++i) {
    int c = tid + 256 * i;
    int row = c >> 2, s = c & 3;
    int sc = s ^ ((row >> 1) & 3);
    Aga[i] = A  + (size_t)(bm + row) * K + sc * 8;
    Bga[i] = Bt + (size_t)(bn + row) * K + sc * 8;
    Ada[i] = &As[0][c * 8];
    Bda[i] = &Bs[0][c * 8];
  }

  int aoff[4], boff[4];
#pragma unroll
  for (int m = 0; m < 4; ++m)
    aoff[m] = (wm * 64 + m * 16 + lrow) * 32 + ((lk ^ ((lrow >> 1) & 3)) * 8);
#pragma unroll
  for (int n = 0; n < 4; ++n)
    boff[n] = (wn * 64 + n * 16 + lrow) * 32 + ((lk ^ ((lrow >> 1) & 3)) * 8);

  f32x4 acc[4][4];
#pragma unroll
  for (int m = 0; m < 4; ++m)
#pragma unroll
    for (int n = 0; n < 4; ++n) acc[m][n] = (f32x4){0.f, 0.f, 0.f, 0.f};

  const int nk = K >> 5;
#pragma unroll
  for (int t = 0; t < 2; ++t) {
#pragma unroll
    for (int i = 0; i < 2; ++i) {
      gll16(Aga[i] + (t << 5), Ada[i] + t * 4096);
      gll16(Bga[i] + (t << 5), Bda[i] + t * 4096);
    }
  }
  int cur = 0, nxt2 = 2;
  for (int kt = 0; kt < nk; ++kt) {
    if (kt + 1 < nk) {
      asm volatile("s_waitcnt vmcnt(4)" ::: "memory");
    } else {
      asm volatile("s_waitcnt vmcnt(0)" ::: "memory");
    }
    __builtin_amdgcn_s_barrier();
    __builtin_amdgcn_sched_barrier(0);
    if (kt + 2 < nk) {
      const int ko = (kt + 2) << 5;
      const int bo = nxt2 * 4096;
#pragma unroll
      for (int i = 0; i < 2; ++i) {
        gll16(Aga[i] + ko, Ada[i] + bo);
        gll16(Bga[i] + ko, Bda[i] + bo);
      }
    }
    __builtin_amdgcn_s_setprio(1);
    {
      short8 af[4], bfr[4];
      const int co = cur * 4096;
#pragma unroll
      for (int m = 0; m < 4; ++m) af[m]  = *(const short8*)&As[0][co + aoff[m]];
#pragma unroll
      for (int n = 0; n < 4; ++n) bfr[n] = *(const short8*)&Bs[0][co + boff[n]];
#pragma unroll
      for (int m = 0; m < 4; ++m)
#pragma unroll
        for (int n = 0; n < 4; ++n)
          acc[m][n] = __builtin_amdgcn_mfma_f32_16x16x32_bf16(af[m], bfr[n], acc[m][n], 0, 0, 0);
    }
    __builtin_amdgcn_s_setprio(0);
    __builtin_amdgcn_sched_barrier(0);
    cur = (cur == 2) ? 0 : cur + 1;
    nxt2 = (nxt2 == 2) ? 0 : nxt2 + 1;
  }

  const int colbase = bn + wn * 64 + lrow;
  const int rowbase = bm + wm * 64 + lk * 4;
#pragma unroll
  for (int m = 0; m < 4; ++m) {
    int row0 = rowbase + m * 16;
#pragma unroll
    for (int n = 0; n < 4; ++n) {
      int col = colbase + n * 16;
      float bv = bvec[col];
#pragma unroll
      for (int r = 0; r < 4; ++r) {
        int row = row0 + r;
        if (row < M) {
          float* p = Cout + (size_t)row * Nn + col;
          *p += acc[m][n][r] + bv;
        }
      }
    }
  }
}

// ------- 8-phase wide bf16 MFMA GEMM: 256x256, BK=64, 8 waves, counted vmcnt -------
template<int MODE>
__global__ __launch_bounds__(512, 2) void mgemm8(const ushort* __restrict__ A,
    const ushort* __restrict__ Bt, const float* __restrict__ bvec,
    void* __restrict__ Cout, int M, int Nn, int K)
{
  __shared__ ushort LS[65536];   // 128 KB
  const int tid = threadIdx.x;
  const int lane = tid & 63, wave = tid >> 6;
  const int wm = wave >> 2, wn = wave & 3;       // 2m x 4n; wave tile 128x64
  const int lrow = lane & 15, lk = lane >> 4;
  const int bm = blockIdx.y * 256;

  const ushort* srcA[2]; const ushort* srcB[2];
  int ldsA[2], ldsB[2];
#pragma unroll
  for (int i = 0; i < 2; ++i) {
    int c = tid + 512 * i, row = c >> 2, s = c & 3;
    int sw = (s ^ ((row >> 1) & 3)) * 8;
    srcA[i] = A + (size_t)(bm + row) * K + sw;
    ldsA[i] = c * 8;
    int gr;
    if (MODE == 3) {
      gr = blockIdx.x * 128 + (row >> 5) * 16 + ((row >> 4) & 1) * 2048 + (row & 15);
    } else {
      gr = blockIdx.x * 256 + row;
    }
    srcB[i] = Bt + (size_t)gr * K + sw;
    ldsB[i] = c * 8;
  }
  int aoff[8], boff[4];
#pragma unroll
  for (int m = 0; m < 8; ++m)
    aoff[m] = (wm * 128 + m * 16 + lrow) * 32 + ((lk ^ ((lrow >> 1) & 3)) * 8);
#pragma unroll
  for (int n = 0; n < 4; ++n)
    boff[n] = (wn * 64 + n * 16 + lrow) * 32 + ((lk ^ ((lrow >> 1) & 3)) * 8);

  f32x4 acc[8][4];
#pragma unroll
  for (int m = 0; m < 8; ++m)
#pragma unroll
    for (int n = 0; n < 4; ++n) acc[m][n] = (f32x4){0.f, 0.f, 0.f, 0.f};

  const int NT = K >> 6;   // 16

#define STG_A(T, H, B)                                                        \
  { _Pragma("unroll")                                                         \
    for (int i = 0; i < 2; ++i)                                               \
      gll16(srcA[i] + ((T) << 6) + ((H) << 5),                                \
            (void*)&LS[((B) * 2 + (H)) * 8192 + ldsA[i]]); }
#define STG_B(T, H, B)                                                        \
  { _Pragma("unroll")                                                         \
    for (int i = 0; i < 2; ++i)                                               \
      gll16(srcB[i] + ((T) << 6) + ((H) << 5),                                \
            (void*)&LS[32768 + ((B) * 2 + (H)) * 8192 + ldsB[i]]); }

#define TILE4(T, B)                                                           \
  {                                                                           \
    const int t_ = (T);                                                       \
    { int ts = (t_ + 1 < NT) ? t_ + 1 : NT - 1; STG_A(ts, 1, (B) ^ 1); }      \
    asm volatile("s_waitcnt vmcnt(10)" ::: "memory");                         \
    __builtin_amdgcn_s_barrier();                                             \
    short8 bfr[4];                                                            \
    _Pragma("unroll")                                                         \
    for (int n = 0; n < 4; ++n)                                               \
      bfr[n] = *(const short8*)&LS[32768 + ((B) * 2 + 0) * 8192 + boff[n]];   \
    {                                                                         \
      short8 af[4];                                                           \
      _Pragma("unroll")                                                       \
      for (int mi = 0; mi < 4; ++mi)                                          \
        af[mi] = *(const short8*)&LS[((B) * 2 + 0) * 8192 + aoff[mi]];        \
      __builtin_amdgcn_s_setprio(1);                                          \
      _Pragma("unroll")                                                       \
      for (int mi = 0; mi < 4; ++mi)                                          \
        _Pragma("unroll")                                                     \
        for (int n = 0; n < 4; ++n)                                           \
          acc[mi][n] = __builtin_amdgcn_mfma_f32_16x16x32_bf16(af[mi], bfr[n], acc[mi][n], 0, 0, 0); \
      __builtin_amdgcn_s_setprio(0);                                          \
    }                                                                         \
    { int ts = (t_ + 1 < NT) ? t_ + 1 : NT - 1; STG_B(ts, 1, (B) ^ 1); }      \
    {                                                                         \
      short8 af[4];                                                           \
      _Pragma("unroll")                                                       \
      for (int mi = 0; mi < 4; ++mi)                                          \
        af[mi] = *(const short8*)&LS[((B) * 2 + 0) * 8192 + aoff[4 + mi]];    \
      __builtin_amdgcn_s_setprio(1);                                          \
      _Pragma("unroll")                                                       \
      for (int mi = 0; mi < 4; ++mi)                                          \
        _Pragma("unroll")                                                     \
        for (int n = 0; n < 4; ++n)                                           \
          acc[4 + mi][n] = __builtin_amdgcn_mfma_f32_16x16x32_bf16(af[mi], bfr[n], acc[4 + mi][n], 0, 0, 0); \
      __builtin_amdgcn_s_setprio(0);                                          \
    }                                                                         \
    __builtin_amdgcn_s_barrier();                                             \
    { int ts = (t_ + 2 < NT) ? t_ + 2 : NT - 1; STG_A(ts, 0, (B)); }          \
    asm volatile("s_waitcnt vmcnt(10)" ::: "memory");                         \
    __builtin_amdgcn_s_barrier();                                             \
    _Pragma("unroll")                                                         \
    for (int n = 0; n < 4; ++n)                                               \
      bfr[n] = *(const short8*)&LS[32768 + ((B) * 2 + 1) * 8192 + boff[n]];   \
    {                                                                         \
      short8 af[4];                                                           \
      _Pragma("unroll")                                                       \
      for (int mi = 0; mi < 4; ++mi)                                          \
        af[mi] = *(const short8*)&LS[((B) * 2 + 1) * 8192 + aoff[mi]];        \
      __builtin_amdgcn_s_setprio(1);                                          \
      _Pragma("unroll")                                                       \
      for (int mi = 0; mi < 4; ++mi)                                          \
        _Pragma("unroll")                                                     \
        for (int n = 0; n < 4; ++n)                                           \
          acc[mi][n] = __builtin_amdgcn_mfma_f32_16x16x32_bf16(af[mi], bfr[n], acc[mi][n], 0, 0, 0); \
      __builtin_amdgcn_s_setprio(0);                                          \
    }                                                                         \
    { int ts = (t_ + 2 < NT) ? t_ + 2 : NT - 1; STG_B(ts, 0, (B)); }          \
    {                                                                         \
      short8 af[4];                                                           \
      _Pragma("unroll")                                                       \
      for (int mi = 0; mi < 4; ++mi)                                          \
        af[mi] = *(const short8*)&LS[((B) * 2 + 1) * 8192 + aoff[4 + mi]];    \
      __builtin_amdgcn_s_setprio(1);                                          \
      _Pragma("unroll")                                                       \
      for (int mi = 0; mi < 4; ++mi)                                          \
        _Pragma("unroll")                                                     \
        for (int n = 0; n < 4; ++n)                                           \
          acc[4 + mi][n] = __builtin_amdgcn_mfma_f32_16x16x32_bf16(af[mi], bfr[n], acc[4 + mi][n], 0, 0, 0); \
      __builtin_amdgcn_s_setprio(0);                                          \
    }                                                                         \
    __builtin_amdgcn_s_barrier();                                             \
  }

  STG_A(0, 0, 0); STG_B(0, 0, 0); STG_A(0, 1, 0); STG_B(0, 1, 0);
  STG_A(1, 0, 1); STG_B(1, 0, 1);
  for (int tt = 0; tt < NT; tt += 2) {
    TILE4(tt, 0);
    TILE4(tt + 1, 1);
  }
#undef TILE4
#undef STG_A
#undef STG_B

  const int rowb0 = bm + wm * 128 + lk * 4;
  if (MODE == 0) {
    const int colb0 = blockIdx.x * 256 + wn * 64 + lrow;
    __hip_bfloat16* Cb = (__hip_bfloat16*)Cout;
#pragma unroll
    for (int m = 0; m < 8; ++m) {
      int row0 = rowb0 + m * 16;
#pragma unroll
      for (int n = 0; n < 4; ++n) {
        int col = colb0 + n * 16;
#pragma unroll
        for (int r = 0; r < 4; ++r) {
          int row = row0 + r;
          if (row < M)
            Cb[(size_t)row * Nn + col] = __float2bfloat16(silu_f(acc[m][n][r]));
        }
      }
    }
  } else {
    __hip_bfloat16* Cb = (__hip_bfloat16*)Cout;   // gated [M][2048]
#pragma unroll
    for (int q = 0; q < 2; ++q) {
      int vcol = blockIdx.x * 128 + (2 * wn + q) * 16 + lrow;
      float bvv = bvec[vcol];
      float bvg = bvec[vcol + 2048];
#pragma unroll
      for (int m = 0; m < 8; ++m) {
        int row0 = rowb0 + m * 16;
#pragma unroll
        for (int r = 0; r < 4; ++r) {
          int row = row0 + r;
          if (row < M) {
            float v = acc[m][2 * q][r] + bvv;
            float g = acc[m][2 * q + 1][r] + bvg;
            Cb[(size_t)row * 2048 + vcol] = __float2bfloat16(silu_f(g) * v);
          }
        }
      }
    }
  }
}

// ---------------- MFMA causal silu-attention (double-buffered K/V, 1 barrier/tile) --
__global__ __launch_bounds__(256) void attn_kernel(const ushort* __restrict__ act,
    const ushort* __restrict__ biasT, ushort* __restrict__ av)
{
  __shared__ __align__(16) char KL[16384];   // 2 bufs x [32 j][128 d] swizzled
  __shared__ __align__(16) char VL[16640];   // 2 bufs x subtiled V (8320 each)
  const int tid = threadIdx.x;
  const int l = tid & 63, w = tid >> 6;
  const int qi = (int)(gridDim.x - 1 - blockIdx.x);
  const int i0 = qi * 128;
  const int h = blockIdx.y, b = blockIdx.z;
  const int lo31 = l & 31, hi = l >> 5;

  const int jlim = (i0 + 128 < SEQN) ? i0 + 128 : SEQN;
  const int nt = (jlim + 31) >> 5;

  const int gi_q = i0 + w * 32 + lo31;
  const int gi_qc = gi_q < SEQN ? gi_q : SEQN - 1;
  const size_t actB = (size_t)b * SEQN;
  const ushort* qrow = act + (actB + gi_qc) * 4096 + h * HD;
  short8 qreg[8];
#pragma unroll
  for (int dc = 0; dc < 8; ++dc)
    qreg[dc] = *(const short8*)(qrow + dc * 16 + hi * 8);

  f32x16 acc[4];
#pragma unroll
  for (int dt = 0; dt < 4; ++dt) acc[dt] = z16();

  const int id0 = tid, id1 = tid + 256;
  const int j_0 = id0 >> 4, c8_0 = (id0 & 15) * 8;
  const int j_1 = id1 >> 4, c8_1 = (id1 & 15) * 8;
  char* kw0 = KL + j_0 * 256 + (((id0 & 15) ^ (j_0 & 15)) << 4);
  char* kw1 = KL + j_1 * 256 + (((id1 & 15) ^ (j_1 & 15)) << 4);
  char* vw0 = VL + ((id0 & 15) >> 1) * 1040 + j_0 * 32 + (id0 & 1) * 16;
  char* vw1 = VL + ((id1 & 15) >> 1) * 1040 + j_1 * 32 + (id1 & 1) * 16;
  const uint vbase0 = (uint)(size_t)(__attribute__((address_space(3))) char*)
      (VL + ((l >> 4) & 1) * 1040 + hi * 256 + (l & 15) * 8);

  short8 kr0, kr1, vr0, vr1;
  {
    const ushort* p0 = act + (actB + j_0) * 4096 + 1024 + h * HD + c8_0;
    const ushort* p1 = act + (actB + j_1) * 4096 + 1024 + h * HD + c8_1;
    kr0 = *(const short8*)p0; vr0 = *(const short8*)(p0 + 1024);
    kr1 = *(const short8*)p1; vr1 = *(const short8*)(p1 + 1024);
  }
  const float invN = 1.f / (float)SEQN;
  const int gi0w = i0 + w * 32;

  for (int t = 0; t < nt; ++t) {
    const int j0 = t * 32;
    const int kb = (t & 1) * 8192;
    const int vb = (t & 1) * 8320;
    *(short8*)(kw0 + kb) = kr0; *(short8*)(kw1 + kb) = kr1;
    *(short8*)(vw0 + vb) = vr0; *(short8*)(vw1 + vb) = vr1;
    __syncthreads();
    if (t + 1 < nt) {
      const ushort* p0 = act + (actB + j0 + 32 + j_0) * 4096 + 1024 + h * HD + c8_0;
      const ushort* p1 = act + (actB + j0 + 32 + j_1) * 4096 + 1024 + h * HD + c8_1;
      kr0 = *(const short8*)p0; vr0 = *(const short8*)(p0 + 1024);
      kr1 = *(const short8*)p1; vr1 = *(const short8*)(p1 + 1024);
    }
    if (j0 <= gi0w + 31 && gi0w < SEQN) {
      float bv[16];
#pragma unroll
      for (int r = 0; r < 16; ++r) {
        int j = (r & 3) + 8 * (r >> 2) + 4 * hi;
        int gj = j0 + j;
        int gjc = gj < SEQN ? gj : SEQN - 1;
        bv[r] = bf2f(biasT[(actB + gjc) * SEQN + gi_qc]);
      }
      f32x16 st = z16();
#pragma unroll
      for (int dc = 0; dc < 8; ++dc) {
        short8 kf = *(const short8*)(KL + kb + lo31 * 256 + ((((dc << 1) + hi) ^ (lo31 & 15)) << 4));
        st = __builtin_amdgcn_mfma_f32_32x32x16_bf16(kf, qreg[dc], st, 0, 0, 0);
      }
      float p[16];
#pragma unroll
      for (int r = 0; r < 16; ++r) {
        int j = (r & 3) + 8 * (r >> 2) + 4 * hi;
        int gj = j0 + j;
        float s = st[r] + bv[r];
        float pw = s * __builtin_amdgcn_rcpf(1.f + __expf(-s)) * invN;
        p[r] = ((gj <= gi_q) && (gi_q < SEQN)) ? pw : 0.f;
      }
      short8 paf[2];
#pragma unroll
      for (int g = 0; g < 2; ++g) {
        uint w0 = pkbf(p[g * 8 + 0], p[g * 8 + 1]);
        uint w2 = pkbf(p[g * 8 + 4], p[g * 8 + 5]);
        uint w1 = pkbf(p[g * 8 + 2], p[g * 8 + 3]);
        uint w3 = pkbf(p[g * 8 + 6], p[g * 8 + 7]);
        asm volatile("v_permlane32_swap_b32 %0, %1" : "+v"(w0), "+v"(w2));
        asm volatile("v_permlane32_swap_b32 %0, %1" : "+v"(w1), "+v"(w3));
        union UF { uint u[4]; short8 s; } uf;
        uf.u[0] = w0; uf.u[1] = w1; uf.u[2] = w2; uf.u[3] = w3;
        paf[g] = uf.s;
      }
      const uint vbase = vbase0 + vb;
      uint64_t v00, v01, v02, v03, v10, v11, v12, v13, v20, v21, v22, v23, v30, v31, v32, v33;
      asm volatile(
        "ds_read_b64_tr_b16 %0, %16 offset:0\n\t"
        "ds_read_b64_tr_b16 %1, %16 offset:128\n\t"
        "ds_read_b64_tr_b16 %2, %16 offset:512\n\t"
        "ds_read_b64_tr_b16 %3, %16 offset:640\n\t"
        "ds_read_b64_tr_b16 %4, %16 offset:2080\n\t"
        "ds_read_b64_tr_b16 %5, %16 offset:2208\n\t"
        "ds_read_b64_tr_b16 %6, %16 offset:2592\n\t"
        "ds_read_b64_tr_b16 %7, %16 offset:2720\n\t"
        "ds_read_b64_tr_b16 %8, %16 offset:4160\n\t"
        "ds_read_b64_tr_b16 %9, %16 offset:4288\n\t"
        "ds_read_b64_tr_b16 %10, %16 offset:4672\n\t"
        "ds_read_b64_tr_b16 %11, %16 offset:4800\n\t"
        "ds_read_b64_tr_b16 %12, %16 offset:6240\n\t"
        "ds_read_b64_tr_b16 %13, %16 offset:6368\n\t"
        "ds_read_b64_tr_b16 %14, %16 offset:6752\n\t"
        "ds_read_b64_tr_b16 %15, %16 offset:6880\n\t"
        "s_waitcnt lgkmcnt(0)"
        : "=v"(v00), "=v"(v01), "=v"(v02), "=v"(v03),
          "=v"(v10), "=v"(v11), "=v"(v12), "=v"(v13),
          "=v"(v20), "=v"(v21), "=v"(v22), "=v"(v23),
          "=v"(v30), "=v"(v31), "=v"(v32), "=v"(v33)
        : "v"(vbase) : "memory");
      union UV { uint64_t q[2]; short8 s; };
      { UV uv; uv.q[0] = v00; uv.q[1] = v01;
        acc[0] = __builtin_amdgcn_mfma_f32_32x32x16_bf16(paf[0], uv.s, acc[0], 0, 0, 0); }
      { UV uv; uv.q[0] = v02; uv.q[1] = v03;
        acc[0] = __builtin_amdgcn_mfma_f32_32x32x16_bf16(paf[1], uv.s, acc[0], 0, 0, 0); }
      { UV uv; uv.q[0] = v10; uv.q[1] = v11;
        acc[1] = __builtin_amdgcn_mfma_f32_32x32x16_bf16(paf[0], uv.s, acc[1], 0, 0, 0); }
      { UV uv; uv.q[0] = v12; uv.q[1] = v13;
        acc[1] = __builtin_amdgcn_mfma_f32_32x32x16_bf16(paf[1], uv.s, acc[1], 0, 0, 0); }
      { UV uv; uv.q[0] = v20; uv.q[1] = v21;
        acc[2] = __builtin_amdgcn_mfma_f32_32x32x16_bf16(paf[0], uv.s, acc[2], 0, 0, 0); }
      { UV uv; uv.q[0] = v22; uv.q[1] = v23;
        acc[2] = __builtin_amdgcn_mfma_f32_32x32x16_bf16(paf[1], uv.s, acc[2], 0, 0, 0); }
      { UV uv; uv.q[0] = v30; uv.q[1] = v31;
        acc[3] = __builtin_amdgcn_mfma_f32_32x32x16_bf16(paf[0], uv.s, acc[3], 0, 0, 0); }
      { UV uv; uv.q[0] = v32; uv.q[1] = v33;
        acc[3] = __builtin_amdgcn_mfma_f32_32x32x16_bf16(paf[1], uv.s, acc[3], 0, 0, 0); }
    }
  }
#pragma unroll
  for (int dt = 0; dt < 4; ++dt) {
#pragma unroll
    for (int r = 0; r < 16; ++r) {
      int q = (r & 3) + 8 * (r >> 2) + 4 * hi;
      int gi = i0 + w * 32 + q;
      if (gi < SEQN)
        av[(actB + gi) * DD + h * HD + dt * 32 + lo31] = f2bf(acc[dt][r]);
    }
  }
}

// ---------------- launch ----------------
extern "C" void kernel_launch(void* const* d_in, const int* in_sizes, int n_in,
                              void* d_out, int out_size, void* d_ws, size_t ws_size,
                              hipStream_t stream) {
  const float* seqs  = (const float*)d_in[0];
  const int*   ts    = (const int*)d_in[2];
  const float* qkvuW = (const float*)d_in[3];
  const float* outW  = (const float*)d_in[4];
  const float* outB  = (const float*)d_in[5];
  const float* tsW   = (const float*)d_in[6];
  const float* posW  = (const float*)d_in[7];
  const float* fc1W  = (const float*)d_in[8];
  const float* fc1B  = (const float*)d_in[9];
  const float* fc2W  = (const float*)d_in[10];
  const float* fc2B  = (const float*)d_in[11];
  float* h = (float*)d_out;
  char* ws = (char*)d_ws;

  ushort* xn    = (ushort*)(ws);                 // 8448*1024*2  = 17,301,504
  ushort* act   = (ushort*)(ws + 17301504);      // 8200*4096*2  = 67,174,400
  ushort* gated = (ushort*)(ws + 84475904);      // 8320*2048*2  = 34,078,720
  ushort* biasT = (ushort*)(ws + 118554624);     // 8*1025*1025*2= 16,810,000
  ushort* av    = (ushort*)(ws + 152174624);     // 8200*1024*2  = 16,793,600
  ushort* wq    = (ushort*)(ws + 185761824);     // 4096*1024*2
  ushort* wo    = (ushort*)(ws + 194150432);     // 1024*1024*2
  ushort* wf1   = (ushort*)(ws + 196247584);     // 4096*1024*2
  ushort* wf2   = (ushort*)(ws + 204636192);     // 1024*2048*2  (end 208,830,496)

  for (int l = 0; l < LL; l++) {
    // fused: 4 weight transposes + bias table (independent outputs, one dispatch)
    prep_kernel<<<52264, 256, 0, stream>>>(
        qkvuW + (size_t)l * DD * 4096, outW + (size_t)l * DD * DD,
        fc1W + (size_t)l * DD * 4096,  fc2W + (size_t)l * 2048 * DD,
        wq, wo, wf1, wf2,
        ts, tsW + l * (NBUCKET + 1), posW + l * (2 * SEQN - 1), biasT);

    if (l == 0)
      lnh_kernel<<<MROWS / 4, 256, 0, stream>>>(seqs, h, xn);   // h = seqs; xn = LN(seqs)
    else
      ln_kernel<<<MROWS / 4, 256, 0, stream>>>(h, xn);
    mgemm8<0><<<dim3(16, 33), 512, 0, stream>>>(xn, wq, nullptr, act, MROWS, 4096, DD);
    attn_kernel<<<dim3(9, HH, BB), 256, 0, stream>>>(act, biasT, av);
    uln_kernel<<<MROWS / 4, 256, 0, stream>>>(av, act, xn);
    mgemm1<<<dim3(8, 65), 256, 0, stream>>>(xn, wo, outB + l * DD, h, MROWS, DD, DD);
    rms_kernel<<<MROWS / 4, 256, 0, stream>>>(h, xn);
    mgemm8<3><<<dim3(16, 33), 512, 0, stream>>>(xn, wf1, fc1B + (size_t)l * 4096, gated, MROWS, 2048, DD);
    mgemm1<<<dim3(8, 65), 256, 0, stream>>>(gated, wf2, fc2B + l * DD, h, MROWS, DD, 2048);
  }
}

// Round 20
// 1019.088 us; speedup vs baseline: 1.0566x; 1.0202x over previous
//
#include <hip/hip_runtime.h>
#include <hip/hip_bf16.h>
#include <math.h>

#define BB 8
#define SEQN 1025
#define DD 1024
#define HH 8
#define HD 128
#define LL 2
#define MROWS (BB*SEQN)     // 8200
#define NBUCKET 64

using short8 = __attribute__((ext_vector_type(8))) short;
using f32x4  = __attribute__((ext_vector_type(4))) float;
using f32x16 = __attribute__((ext_vector_type(16))) float;

__device__ __forceinline__ float silu_f(float x) { return x / (1.f + expf(-x)); }

__device__ __forceinline__ float bf2f(ushort u) {
  union { uint i; float f; } x; x.i = ((uint)u) << 16; return x.f;
}
__device__ __forceinline__ ushort f2bf(float f) {
  __hip_bfloat16 b = __float2bfloat16(f);
  return *reinterpret_cast<ushort*>(&b);
}
__device__ __forceinline__ void gll16(const void* g, void* l) {
  __builtin_amdgcn_global_load_lds((const __attribute__((address_space(1))) void*)g,
                                   (__attribute__((address_space(3))) void*)l, 16, 0, 0);
}
__device__ __forceinline__ uint pkbf(float lo, float hi) {
  uint r;
  asm("v_cvt_pk_bf16_f32 %0, %1, %2" : "=v"(r) : "v"(lo), "v"(hi));
  return r;
}
__device__ __forceinline__ f32x16 z16() {
  f32x16 v;
#pragma unroll
  for (int i = 0; i < 16; ++i) v[i] = 0.f;
  return v;
}

// ======== front dispatch: BOTH layers' prep (4 transposes + bias) + layer-0 lnh =====
// Segments per layer (52,264 blocks): [0,4096) wq | [4096,8192) wf1 |
// [8192,10240) wf2 | [10240,11264) wo | [11264,52264) bias.
// Blocks [104528, 106578): lnh (h=seqs; xn=LN(seqs)), 4 rows/block.
// All segments read ONLY kernel inputs; outputs disjoint (double-buffered weight
// and bias sets per layer) -> race-free in one dispatch.
__device__ __forceinline__ void wtrans_blk(const float* __restrict__ W,
    ushort* __restrict__ Wt, int K, int N, int bx, int by, int tid,
    float tile[32][33]) {
  const int tx = tid & 31, ty = tid >> 5;           // 32 x 8
  const int n0 = bx * 32, k0 = by * 32;
#pragma unroll
  for (int r = 0; r < 32; r += 8)
    tile[ty + r][tx] = W[(size_t)(k0 + ty + r) * N + n0 + tx];
  __syncthreads();
#pragma unroll
  for (int r = 0; r < 32; r += 8)
    Wt[(size_t)(n0 + ty + r) * K + k0 + tx] = f2bf(tile[tx][ty + r]);
}

__global__ __launch_bounds__(256) void prep2_kernel(
    const float* __restrict__ qkvuW, const float* __restrict__ outW,
    const float* __restrict__ fc1W,  const float* __restrict__ fc2W,
    ushort* __restrict__ wq0, ushort* __restrict__ wo0,
    ushort* __restrict__ wf10, ushort* __restrict__ wf20,
    ushort* __restrict__ wq1, ushort* __restrict__ wo1,
    ushort* __restrict__ wf11, ushort* __restrict__ wf21,
    const int* __restrict__ ts, const float* __restrict__ tsW,
    const float* __restrict__ posW,
    ushort* __restrict__ biasT0, ushort* __restrict__ biasT1,
    const float* __restrict__ seqs, float* __restrict__ hout,
    ushort* __restrict__ xn)
{
  __shared__ float tile[32][33];
  const int bid = blockIdx.x;
  const int tid = threadIdx.x;
  if (bid < 104528) {
    const int L = bid / 52264;
    const int r = bid % 52264;
    const float* qW = qkvuW + (size_t)L * DD * 4096;
    const float* oW = outW  + (size_t)L * DD * DD;
    const float* f1 = fc1W  + (size_t)L * DD * 4096;
    const float* f2 = fc2W  + (size_t)L * 2048 * DD;
    ushort* wq  = L ? wq1  : wq0;
    ushort* wo  = L ? wo1  : wo0;
    ushort* wf1 = L ? wf11 : wf10;
    ushort* wf2 = L ? wf21 : wf20;
    if (r < 4096) {
      wtrans_blk(qW, wq, 1024, 4096, r & 127, r >> 7, tid, tile);
    } else if (r < 8192) {
      const int b2 = r - 4096;
      wtrans_blk(f1, wf1, 1024, 4096, b2 & 127, b2 >> 7, tid, tile);
    } else if (r < 10240) {
      const int b3 = r - 8192;
      wtrans_blk(f2, wf2, 2048, 1024, b3 & 31, b3 >> 5, tid, tile);
    } else if (r < 11264) {
      const int b4 = r - 10240;
      wtrans_blk(oW, wo, 1024, 1024, b4 & 31, b4 >> 5, tid, tile);
    } else {
      const int b5 = r - 11264;                  // [0, 41000)
      const int b  = b5 / 5125;
      const int rem = b5 % 5125;
      const int j  = rem / 5;
      const int i  = (rem % 5) * 256 + tid;
      if (i >= SEQN) return;
      const float* ts_w  = tsW  + L * (NBUCKET + 1);
      const float* pos_w = posW + L * (2 * SEQN - 1);
      ushort* biasT = L ? biasT1 : biasT0;
      int ip1 = i + 1; if (ip1 > SEQN - 1) ip1 = SEQN - 1;
      long long t1 = (long long)ts[b * SEQN + ip1];
      long long t0 = (long long)ts[b * SEQN + j];
      long long d = t1 - t0;
      if (d < 0) d = -d;
      if (d < 1) d = 1;
      int bucket = (int)(logf((float)d) / 0.301f);
      if (bucket < 0) bucket = 0;
      if (bucket > NBUCKET) bucket = NBUCKET;
      biasT[((size_t)(b * SEQN + j)) * SEQN + i] = f2bf(pos_w[j - i + SEQN - 1] + ts_w[bucket]);
    }
  } else {
    // lnh: h = seqs; xn = LN(seqs).  4 rows/block, wave-per-row.
    const int row = (bid - 104528) * 4 + (tid >> 6);
    const int lane = tid & 63;
    const float* x = seqs + (size_t)row * DD;
    float4 v[4];
    float s = 0.f, ss = 0.f;
#pragma unroll
    for (int i = 0; i < 4; ++i) {
      v[i] = *(const float4*)&x[(lane + i * 64) * 4];
      s  += v[i].x + v[i].y + v[i].z + v[i].w;
      ss += v[i].x*v[i].x + v[i].y*v[i].y + v[i].z*v[i].z + v[i].w*v[i].w;
    }
#pragma unroll
    for (int off = 32; off >= 1; off >>= 1) { s += __shfl_xor(s, off); ss += __shfl_xor(ss, off); }
    float mu = s * (1.f / DD);
    float var = fmaxf(ss * (1.f / DD) - mu * mu, 0.f);
    float inv = 1.f / sqrtf(var + 1e-8f);
#pragma unroll
    for (int i = 0; i < 4; ++i) {
      *(float4*)&hout[(size_t)row * DD + (lane + i * 64) * 4] = v[i];
      ushort4 o;
      o.x = f2bf((v[i].x - mu) * inv); o.y = f2bf((v[i].y - mu) * inv);
      o.z = f2bf((v[i].z - mu) * inv); o.w = f2bf((v[i].w - mu) * inv);
      *(ushort4*)&xn[(size_t)row * DD + (lane + i * 64) * 4] = o;
    }
  }
}

// ============ norm family: wave-per-row, 4 rows/block, no barriers ============
__global__ __launch_bounds__(256) void ln_kernel(const float* __restrict__ in,
                                                 ushort* __restrict__ out) {
  const int row = blockIdx.x * 4 + (threadIdx.x >> 6);
  const int lane = threadIdx.x & 63;
  const float* x = in + (size_t)row * DD;
  float4 v[4];
  float s = 0.f, ss = 0.f;
#pragma unroll
  for (int i = 0; i < 4; ++i) {
    v[i] = *(const float4*)&x[(lane + i * 64) * 4];
    s  += v[i].x + v[i].y + v[i].z + v[i].w;
    ss += v[i].x*v[i].x + v[i].y*v[i].y + v[i].z*v[i].z + v[i].w*v[i].w;
  }
#pragma unroll
  for (int off = 32; off >= 1; off >>= 1) { s += __shfl_xor(s, off); ss += __shfl_xor(ss, off); }
  float mu = s * (1.f / DD);
  float var = fmaxf(ss * (1.f / DD) - mu * mu, 0.f);
  float inv = 1.f / sqrtf(var + 1e-8f);
#pragma unroll
  for (int i = 0; i < 4; ++i) {
    ushort4 o;
    o.x = f2bf((v[i].x - mu) * inv); o.y = f2bf((v[i].y - mu) * inv);
    o.z = f2bf((v[i].z - mu) * inv); o.w = f2bf((v[i].w - mu) * inv);
    *(ushort4*)&out[(size_t)row * DD + (lane + i * 64) * 4] = o;
  }
}

__global__ __launch_bounds__(256) void rms_kernel(const float* __restrict__ in,
                                                  ushort* __restrict__ out) {
  const int row = blockIdx.x * 4 + (threadIdx.x >> 6);
  const int lane = threadIdx.x & 63;
  const float* x = in + (size_t)row * DD;
  float4 v[4];
  float ss = 0.f;
#pragma unroll
  for (int i = 0; i < 4; ++i) {
    v[i] = *(const float4*)&x[(lane + i * 64) * 4];
    ss += v[i].x*v[i].x + v[i].y*v[i].y + v[i].z*v[i].z + v[i].w*v[i].w;
  }
#pragma unroll
  for (int off = 32; off >= 1; off >>= 1) ss += __shfl_xor(ss, off);
  float inv = 1.f / sqrtf(ss * (1.f / DD) + 1e-8f);
#pragma unroll
  for (int i = 0; i < 4; ++i) {
    ushort4 o;
    o.x = f2bf(v[i].x * inv); o.y = f2bf(v[i].y * inv);
    o.z = f2bf(v[i].z * inv); o.w = f2bf(v[i].w * inv);
    *(ushort4*)&out[(size_t)row * DD + (lane + i * 64) * 4] = o;
  }
}

__global__ __launch_bounds__(256) void uln_kernel(const ushort* __restrict__ av,
    const ushort* __restrict__ act, ushort* __restrict__ out) {
  const int row = blockIdx.x * 4 + (threadIdx.x >> 6);
  const int lane = threadIdx.x & 63;
  float4 v[4];
  float s = 0.f, ss = 0.f;
#pragma unroll
  for (int i = 0; i < 4; ++i) {
    ushort4 ub = *(const ushort4*)&av[(size_t)row * DD + (lane + i * 64) * 4];
    v[i].x = bf2f(ub.x); v[i].y = bf2f(ub.y); v[i].z = bf2f(ub.z); v[i].w = bf2f(ub.w);
    s  += v[i].x + v[i].y + v[i].z + v[i].w;
    ss += v[i].x*v[i].x + v[i].y*v[i].y + v[i].z*v[i].z + v[i].w*v[i].w;
  }
#pragma unroll
  for (int off = 32; off >= 1; off >>= 1) { s += __shfl_xor(s, off); ss += __shfl_xor(ss, off); }
  float mu = s * (1.f / DD);
  float var = fmaxf(ss * (1.f / DD) - mu * mu, 0.f);
  float inv = 1.f / sqrtf(var + 1e-8f);
#pragma unroll
  for (int i = 0; i < 4; ++i) {
    ushort4 uu = *(const ushort4*)&act[(size_t)row * 4096 + 3072 + (lane + i * 64) * 4];
    ushort4 o;
    o.x = f2bf(bf2f(uu.x) * (v[i].x - mu) * inv);
    o.y = f2bf(bf2f(uu.y) * (v[i].y - mu) * inv);
    o.z = f2bf(bf2f(uu.z) * (v[i].z - mu) * inv);
    o.w = f2bf(bf2f(uu.w) * (v[i].w - mu) * inv);
    *(ushort4*)&out[(size_t)row * DD + (lane + i * 64) * 4] = o;
  }
}

// ---------------- bf16 MFMA GEMM (BK=32, 3-buffer depth-2 pipeline), 256 thr ----
__global__ __launch_bounds__(256) void mgemm1(const ushort* __restrict__ A,
    const ushort* __restrict__ Bt, const float* __restrict__ bvec,
    float* __restrict__ Cout, int M, int Nn, int K)
{
  __shared__ ushort As[3][4096];
  __shared__ ushort Bs[3][4096];
  const int tid  = threadIdx.x;
  const int lane = tid & 63, wave = tid >> 6;
  const int wm = wave >> 1, wn = wave & 1;
  const int lrow = lane & 15, lk = lane >> 4;
  const int bm = blockIdx.y * 128, bn = blockIdx.x * 128;

  const ushort* Aga[2]; const ushort* Bga[2];
  ushort* Ada[2]; ushort* Bda[2];
#pragma unroll
  for (int i = 0; i < 2; ++i) {
    int c = tid + 256 * i;
    int row = c >> 2, s = c & 3;
    int sc = s ^ ((row >> 1) & 3);
    Aga[i] = A  + (size_t)(bm + row) * K + sc * 8;
    Bga[i] = Bt + (size_t)(bn + row) * K + sc * 8;
    Ada[i] = &As[0][c * 8];
    Bda[i] = &Bs[0][c * 8];
  }

  int aoff[4], boff[4];
#pragma unroll
  for (int m = 0; m < 4; ++m)
    aoff[m] = (wm * 64 + m * 16 + lrow) * 32 + ((lk ^ ((lrow >> 1) & 3)) * 8);
#pragma unroll
  for (int n = 0; n < 4; ++n)
    boff[n] = (wn * 64 + n * 16 + lrow) * 32 + ((lk ^ ((lrow >> 1) & 3)) * 8);

  f32x4 acc[4][4];
#pragma unroll
  for (int m = 0; m < 4; ++m)
#pragma unroll
    for (int n = 0; n < 4; ++n) acc[m][n] = (f32x4){0.f, 0.f, 0.f, 0.f};

  const int nk = K >> 5;
#pragma unroll
  for (int t = 0; t < 2; ++t) {
#pragma unroll
    for (int i = 0; i < 2; ++i) {
      gll16(Aga[i] + (t << 5), Ada[i] + t * 4096);
      gll16(Bga[i] + (t << 5), Bda[i] + t * 4096);
    }
  }
  int cur = 0, nxt2 = 2;
  for (int kt = 0; kt < nk; ++kt) {
    if (kt + 1 < nk) {
      asm volatile("s_waitcnt vmcnt(4)" ::: "memory");
    } else {
      asm volatile("s_waitcnt vmcnt(0)" ::: "memory");
    }
    __builtin_amdgcn_s_barrier();
    __builtin_amdgcn_sched_barrier(0);
    if (kt + 2 < nk) {
      const int ko = (kt + 2) << 5;
      const int bo = nxt2 * 4096;
#pragma unroll
      for (int i = 0; i < 2; ++i) {
        gll16(Aga[i] + ko, Ada[i] + bo);
        gll16(Bga[i] + ko, Bda[i] + bo);
      }
    }
    __builtin_amdgcn_s_setprio(1);
    {
      short8 af[4], bfr[4];
      const int co = cur * 4096;
#pragma unroll
      for (int m = 0; m < 4; ++m) af[m]  = *(const short8*)&As[0][co + aoff[m]];
#pragma unroll
      for (int n = 0; n < 4; ++n) bfr[n] = *(const short8*)&Bs[0][co + boff[n]];
#pragma unroll
      for (int m = 0; m < 4; ++m)
#pragma unroll
        for (int n = 0; n < 4; ++n)
          acc[m][n] = __builtin_amdgcn_mfma_f32_16x16x32_bf16(af[m], bfr[n], acc[m][n], 0, 0, 0);
    }
    __builtin_amdgcn_s_setprio(0);
    __builtin_amdgcn_sched_barrier(0);
    cur = (cur == 2) ? 0 : cur + 1;
    nxt2 = (nxt2 == 2) ? 0 : nxt2 + 1;
  }

  const int colbase = bn + wn * 64 + lrow;
  const int rowbase = bm + wm * 64 + lk * 4;
#pragma unroll
  for (int m = 0; m < 4; ++m) {
    int row0 = rowbase + m * 16;
#pragma unroll
    for (int n = 0; n < 4; ++n) {
      int col = colbase + n * 16;
      float bv = bvec[col];
#pragma unroll
      for (int r = 0; r < 4; ++r) {
        int row = row0 + r;
        if (row < M) {
          float* p = Cout + (size_t)row * Nn + col;
          *p += acc[m][n][r] + bv;
        }
      }
    }
  }
}

// ------- 8-phase wide bf16 MFMA GEMM: 256x256, BK=64, 8 waves, counted vmcnt -------
template<int MODE>
__global__ __launch_bounds__(512, 2) void mgemm8(const ushort* __restrict__ A,
    const ushort* __restrict__ Bt, const float* __restrict__ bvec,
    void* __restrict__ Cout, int M, int Nn, int K)
{
  __shared__ ushort LS[65536];   // 128 KB
  const int tid = threadIdx.x;
  const int lane = tid & 63, wave = tid >> 6;
  const int wm = wave >> 2, wn = wave & 3;       // 2m x 4n; wave tile 128x64
  const int lrow = lane & 15, lk = lane >> 4;
  const int bm = blockIdx.y * 256;

  const ushort* srcA[2]; const ushort* srcB[2];
  int ldsA[2], ldsB[2];
#pragma unroll
  for (int i = 0; i < 2; ++i) {
    int c = tid + 512 * i, row = c >> 2, s = c & 3;
    int sw = (s ^ ((row >> 1) & 3)) * 8;
    srcA[i] = A + (size_t)(bm + row) * K + sw;
    ldsA[i] = c * 8;
    int gr;
    if (MODE == 3) {
      gr = blockIdx.x * 128 + (row >> 5) * 16 + ((row >> 4) & 1) * 2048 + (row & 15);
    } else {
      gr = blockIdx.x * 256 + row;
    }
    srcB[i] = Bt + (size_t)gr * K + sw;
    ldsB[i] = c * 8;
  }
  int aoff[8], boff[4];
#pragma unroll
  for (int m = 0; m < 8; ++m)
    aoff[m] = (wm * 128 + m * 16 + lrow) * 32 + ((lk ^ ((lrow >> 1) & 3)) * 8);
#pragma unroll
  for (int n = 0; n < 4; ++n)
    boff[n] = (wn * 64 + n * 16 + lrow) * 32 + ((lk ^ ((lrow >> 1) & 3)) * 8);

  f32x4 acc[8][4];
#pragma unroll
  for (int m = 0; m < 8; ++m)
#pragma unroll
    for (int n = 0; n < 4; ++n) acc[m][n] = (f32x4){0.f, 0.f, 0.f, 0.f};

  const int NT = K >> 6;   // 16

#define STG_A(T, H, B)                                                        \
  { _Pragma("unroll")                                                         \
    for (int i = 0; i < 2; ++i)                                               \
      gll16(srcA[i] + ((T) << 6) + ((H) << 5),                                \
            (void*)&LS[((B) * 2 + (H)) * 8192 + ldsA[i]]); }
#define STG_B(T, H, B)                                                        \
  { _Pragma("unroll")                                                         \
    for (int i = 0; i < 2; ++i)                                               \
      gll16(srcB[i] + ((T) << 6) + ((H) << 5),                                \
            (void*)&LS[32768 + ((B) * 2 + (H)) * 8192 + ldsB[i]]); }

#define TILE4(T, B)                                                           \
  {                                                                           \
    const int t_ = (T);                                                       \
    { int ts = (t_ + 1 < NT) ? t_ + 1 : NT - 1; STG_A(ts, 1, (B) ^ 1); }      \
    asm volatile("s_waitcnt vmcnt(10)" ::: "memory");                         \
    __builtin_amdgcn_s_barrier();                                             \
    short8 bfr[4];                                                            \
    _Pragma("unroll")                                                         \
    for (int n = 0; n < 4; ++n)                                               \
      bfr[n] = *(const short8*)&LS[32768 + ((B) * 2 + 0) * 8192 + boff[n]];   \
    {                                                                         \
      short8 af[4];                                                           \
      _Pragma("unroll")                                                       \
      for (int mi = 0; mi < 4; ++mi)                                          \
        af[mi] = *(const short8*)&LS[((B) * 2 + 0) * 8192 + aoff[mi]];        \
      __builtin_amdgcn_s_setprio(1);                                          \
      _Pragma("unroll")                                                       \
      for (int mi = 0; mi < 4; ++mi)                                          \
        _Pragma("unroll")                                                     \
        for (int n = 0; n < 4; ++n)                                           \
          acc[mi][n] = __builtin_amdgcn_mfma_f32_16x16x32_bf16(af[mi], bfr[n], acc[mi][n], 0, 0, 0); \
      __builtin_amdgcn_s_setprio(0);                                          \
    }                                                                         \
    { int ts = (t_ + 1 < NT) ? t_ + 1 : NT - 1; STG_B(ts, 1, (B) ^ 1); }      \
    {                                                                         \
      short8 af[4];                                                           \
      _Pragma("unroll")                                                       \
      for (int mi = 0; mi < 4; ++mi)                                          \
        af[mi] = *(const short8*)&LS[((B) * 2 + 0) * 8192 + aoff[4 + mi]];    \
      __builtin_amdgcn_s_setprio(1);                                          \
      _Pragma("unroll")                                                       \
      for (int mi = 0; mi < 4; ++mi)                                          \
        _Pragma("unroll")                                                     \
        for (int n = 0; n < 4; ++n)                                           \
          acc[4 + mi][n] = __builtin_amdgcn_mfma_f32_16x16x32_bf16(af[mi], bfr[n], acc[4 + mi][n], 0, 0, 0); \
      __builtin_amdgcn_s_setprio(0);                                          \
    }                                                                         \
    __builtin_amdgcn_s_barrier();                                             \
    { int ts = (t_ + 2 < NT) ? t_ + 2 : NT - 1; STG_A(ts, 0, (B)); }          \
    asm volatile("s_waitcnt vmcnt(10)" ::: "memory");                         \
    __builtin_amdgcn_s_barrier();                                             \
    _Pragma("unroll")                                                         \
    for (int n = 0; n < 4; ++n)                                               \
      bfr[n] = *(const short8*)&LS[32768 + ((B) * 2 + 1) * 8192 + boff[n]];   \
    {                                                                         \
      short8 af[4];                                                           \
      _Pragma("unroll")                                                       \
      for (int mi = 0; mi < 4; ++mi)                                          \
        af[mi] = *(const short8*)&LS[((B) * 2 + 1) * 8192 + aoff[mi]];        \
      __builtin_amdgcn_s_setprio(1);                                          \
      _Pragma("unroll")                                                       \
      for (int mi = 0; mi < 4; ++mi)                                          \
        _Pragma("unroll")                                                     \
        for (int n = 0; n < 4; ++n)                                           \
          acc[mi][n] = __builtin_amdgcn_mfma_f32_16x16x32_bf16(af[mi], bfr[n], acc[mi][n], 0, 0, 0); \
      __builtin_amdgcn_s_setprio(0);                                          \
    }                                                                         \
    { int ts = (t_ + 2 < NT) ? t_ + 2 : NT - 1; STG_B(ts, 0, (B)); }          \
    {                                                                         \
      short8 af[4];                                                           \
      _Pragma("unroll")                                                       \
      for (int mi = 0; mi < 4; ++mi)                                          \
        af[mi] = *(const short8*)&LS[((B) * 2 + 1) * 8192 + aoff[4 + mi]];    \
      __builtin_amdgcn_s_setprio(1);                                          \
      _Pragma("unroll")                                                       \
      for (int mi = 0; mi < 4; ++mi)                                          \
        _Pragma("unroll")                                                     \
        for (int n = 0; n < 4; ++n)                                           \
          acc[4 + mi][n] = __builtin_amdgcn_mfma_f32_16x16x32_bf16(af[mi], bfr[n], acc[4 + mi][n], 0, 0, 0); \
      __builtin_amdgcn_s_setprio(0);                                          \
    }                                                                         \
    __builtin_amdgcn_s_barrier();                                             \
  }

  STG_A(0, 0, 0); STG_B(0, 0, 0); STG_A(0, 1, 0); STG_B(0, 1, 0);
  STG_A(1, 0, 1); STG_B(1, 0, 1);
  for (int tt = 0; tt < NT; tt += 2) {
    TILE4(tt, 0);
    TILE4(tt + 1, 1);
  }
#undef TILE4
#undef STG_A
#undef STG_B

  const int rowb0 = bm + wm * 128 + lk * 4;
  if (MODE == 0) {
    const int colb0 = blockIdx.x * 256 + wn * 64 + lrow;
    __hip_bfloat16* Cb = (__hip_bfloat16*)Cout;
#pragma unroll
    for (int m = 0; m < 8; ++m) {
      int row0 = rowb0 + m * 16;
#pragma unroll
      for (int n = 0; n < 4; ++n) {
        int col = colb0 + n * 16;
#pragma unroll
        for (int r = 0; r < 4; ++r) {
          int row = row0 + r;
          if (row < M)
            Cb[(size_t)row * Nn + col] = __float2bfloat16(silu_f(acc[m][n][r]));
        }
      }
    }
  } else {
    __hip_bfloat16* Cb = (__hip_bfloat16*)Cout;   // gated [M][2048]
#pragma unroll
    for (int q = 0; q < 2; ++q) {
      int vcol = blockIdx.x * 128 + (2 * wn + q) * 16 + lrow;
      float bvv = bvec[vcol];
      float bvg = bvec[vcol + 2048];
#pragma unroll
      for (int m = 0; m < 8; ++m) {
        int row0 = rowb0 + m * 16;
#pragma unroll
        for (int r = 0; r < 4; ++r) {
          int row = row0 + r;
          if (row < M) {
            float v = acc[m][2 * q][r] + bvv;
            float g = acc[m][2 * q + 1][r] + bvg;
            Cb[(size_t)row * 2048 + vcol] = __float2bfloat16(silu_f(g) * v);
          }
        }
      }
    }
  }
}

// ---------------- MFMA causal silu-attention (double-buffered K/V, 1 barrier/tile) --
__global__ __launch_bounds__(256) void attn_kernel(const ushort* __restrict__ act,
    const ushort* __restrict__ biasT, ushort* __restrict__ av)
{
  __shared__ __align__(16) char KL[16384];   // 2 bufs x [32 j][128 d] swizzled
  __shared__ __align__(16) char VL[16640];   // 2 bufs x subtiled V (8320 each)
  const int tid = threadIdx.x;
  const int l = tid & 63, w = tid >> 6;
  const int qi = (int)(gridDim.x - 1 - blockIdx.x);
  const int i0 = qi * 128;
  const int h = blockIdx.y, b = blockIdx.z;
  const int lo31 = l & 31, hi = l >> 5;

  const int jlim = (i0 + 128 < SEQN) ? i0 + 128 : SEQN;
  const int nt = (jlim + 31) >> 5;

  const int gi_q = i0 + w * 32 + lo31;
  const int gi_qc = gi_q < SEQN ? gi_q : SEQN - 1;
  const size_t actB = (size_t)b * SEQN;
  const ushort* qrow = act + (actB + gi_qc) * 4096 + h * HD;
  short8 qreg[8];
#pragma unroll
  for (int dc = 0; dc < 8; ++dc)
    qreg[dc] = *(const short8*)(qrow + dc * 16 + hi * 8);

  f32x16 acc[4];
#pragma unroll
  for (int dt = 0; dt < 4; ++dt) acc[dt] = z16();

  const int id0 = tid, id1 = tid + 256;
  const int j_0 = id0 >> 4, c8_0 = (id0 & 15) * 8;
  const int j_1 = id1 >> 4, c8_1 = (id1 & 15) * 8;
  char* kw0 = KL + j_0 * 256 + (((id0 & 15) ^ (j_0 & 15)) << 4);
  char* kw1 = KL + j_1 * 256 + (((id1 & 15) ^ (j_1 & 15)) << 4);
  char* vw0 = VL + ((id0 & 15) >> 1) * 1040 + j_0 * 32 + (id0 & 1) * 16;
  char* vw1 = VL + ((id1 & 15) >> 1) * 1040 + j_1 * 32 + (id1 & 1) * 16;
  const uint vbase0 = (uint)(size_t)(__attribute__((address_space(3))) char*)
      (VL + ((l >> 4) & 1) * 1040 + hi * 256 + (l & 15) * 8);

  short8 kr0, kr1, vr0, vr1;
  {
    const ushort* p0 = act + (actB + j_0) * 4096 + 1024 + h * HD + c8_0;
    const ushort* p1 = act + (actB + j_1) * 4096 + 1024 + h * HD + c8_1;
    kr0 = *(const short8*)p0; vr0 = *(const short8*)(p0 + 1024);
    kr1 = *(const short8*)p1; vr1 = *(const short8*)(p1 + 1024);
  }
  const float invN = 1.f / (float)SEQN;
  const int gi0w = i0 + w * 32;

  for (int t = 0; t < nt; ++t) {
    const int j0 = t * 32;
    const int kb = (t & 1) * 8192;
    const int vb = (t & 1) * 8320;
    *(short8*)(kw0 + kb) = kr0; *(short8*)(kw1 + kb) = kr1;
    *(short8*)(vw0 + vb) = vr0; *(short8*)(vw1 + vb) = vr1;
    __syncthreads();
    if (t + 1 < nt) {
      const ushort* p0 = act + (actB + j0 + 32 + j_0) * 4096 + 1024 + h * HD + c8_0;
      const ushort* p1 = act + (actB + j0 + 32 + j_1) * 4096 + 1024 + h * HD + c8_1;
      kr0 = *(const short8*)p0; vr0 = *(const short8*)(p0 + 1024);
      kr1 = *(const short8*)p1; vr1 = *(const short8*)(p1 + 1024);
    }
    if (j0 <= gi0w + 31 && gi0w < SEQN) {
      float bv[16];
#pragma unroll
      for (int r = 0; r < 16; ++r) {
        int j = (r & 3) + 8 * (r >> 2) + 4 * hi;
        int gj = j0 + j;
        int gjc = gj < SEQN ? gj : SEQN - 1;
        bv[r] = bf2f(biasT[(actB + gjc) * SEQN + gi_qc]);
      }
      f32x16 st = z16();
#pragma unroll
      for (int dc = 0; dc < 8; ++dc) {
        short8 kf = *(const short8*)(KL + kb + lo31 * 256 + ((((dc << 1) + hi) ^ (lo31 & 15)) << 4));
        st = __builtin_amdgcn_mfma_f32_32x32x16_bf16(kf, qreg[dc], st, 0, 0, 0);
      }
      float p[16];
#pragma unroll
      for (int r = 0; r < 16; ++r) {
        int j = (r & 3) + 8 * (r >> 2) + 4 * hi;
        int gj = j0 + j;
        float s = st[r] + bv[r];
        float pw = s * __builtin_amdgcn_rcpf(1.f + __expf(-s)) * invN;
        p[r] = ((gj <= gi_q) && (gi_q < SEQN)) ? pw : 0.f;
      }
      short8 paf[2];
#pragma unroll
      for (int g = 0; g < 2; ++g) {
        uint w0 = pkbf(p[g * 8 + 0], p[g * 8 + 1]);
        uint w2 = pkbf(p[g * 8 + 4], p[g * 8 + 5]);
        uint w1 = pkbf(p[g * 8 + 2], p[g * 8 + 3]);
        uint w3 = pkbf(p[g * 8 + 6], p[g * 8 + 7]);
        asm volatile("v_permlane32_swap_b32 %0, %1" : "+v"(w0), "+v"(w2));
        asm volatile("v_permlane32_swap_b32 %0, %1" : "+v"(w1), "+v"(w3));
        union UF { uint u[4]; short8 s; } uf;
        uf.u[0] = w0; uf.u[1] = w1; uf.u[2] = w2; uf.u[3] = w3;
        paf[g] = uf.s;
      }
      const uint vbase = vbase0 + vb;
      uint64_t v00, v01, v02, v03, v10, v11, v12, v13, v20, v21, v22, v23, v30, v31, v32, v33;
      asm volatile(
        "ds_read_b64_tr_b16 %0, %16 offset:0\n\t"
        "ds_read_b64_tr_b16 %1, %16 offset:128\n\t"
        "ds_read_b64_tr_b16 %2, %16 offset:512\n\t"
        "ds_read_b64_tr_b16 %3, %16 offset:640\n\t"
        "ds_read_b64_tr_b16 %4, %16 offset:2080\n\t"
        "ds_read_b64_tr_b16 %5, %16 offset:2208\n\t"
        "ds_read_b64_tr_b16 %6, %16 offset:2592\n\t"
        "ds_read_b64_tr_b16 %7, %16 offset:2720\n\t"
        "ds_read_b64_tr_b16 %8, %16 offset:4160\n\t"
        "ds_read_b64_tr_b16 %9, %16 offset:4288\n\t"
        "ds_read_b64_tr_b16 %10, %16 offset:4672\n\t"
        "ds_read_b64_tr_b16 %11, %16 offset:4800\n\t"
        "ds_read_b64_tr_b16 %12, %16 offset:6240\n\t"
        "ds_read_b64_tr_b16 %13, %16 offset:6368\n\t"
        "ds_read_b64_tr_b16 %14, %16 offset:6752\n\t"
        "ds_read_b64_tr_b16 %15, %16 offset:6880\n\t"
        "s_waitcnt lgkmcnt(0)"
        : "=v"(v00), "=v"(v01), "=v"(v02), "=v"(v03),
          "=v"(v10), "=v"(v11), "=v"(v12), "=v"(v13),
          "=v"(v20), "=v"(v21), "=v"(v22), "=v"(v23),
          "=v"(v30), "=v"(v31), "=v"(v32), "=v"(v33)
        : "v"(vbase) : "memory");
      union UV { uint64_t q[2]; short8 s; };
      { UV uv; uv.q[0] = v00; uv.q[1] = v01;
        acc[0] = __builtin_amdgcn_mfma_f32_32x32x16_bf16(paf[0], uv.s, acc[0], 0, 0, 0); }
      { UV uv; uv.q[0] = v02; uv.q[1] = v03;
        acc[0] = __builtin_amdgcn_mfma_f32_32x32x16_bf16(paf[1], uv.s, acc[0], 0, 0, 0); }
      { UV uv; uv.q[0] = v10; uv.q[1] = v11;
        acc[1] = __builtin_amdgcn_mfma_f32_32x32x16_bf16(paf[0], uv.s, acc[1], 0, 0, 0); }
      { UV uv; uv.q[0] = v12; uv.q[1] = v13;
        acc[1] = __builtin_amdgcn_mfma_f32_32x32x16_bf16(paf[1], uv.s, acc[1], 0, 0, 0); }
      { UV uv; uv.q[0] = v20; uv.q[1] = v21;
        acc[2] = __builtin_amdgcn_mfma_f32_32x32x16_bf16(paf[0], uv.s, acc[2], 0, 0, 0); }
      { UV uv; uv.q[0] = v22; uv.q[1] = v23;
        acc[2] = __builtin_amdgcn_mfma_f32_32x32x16_bf16(paf[1], uv.s, acc[2], 0, 0, 0); }
      { UV uv; uv.q[0] = v30; uv.q[1] = v31;
        acc[3] = __builtin_amdgcn_mfma_f32_32x32x16_bf16(paf[0], uv.s, acc[3], 0, 0, 0); }
      { UV uv; uv.q[0] = v32; uv.q[1] = v33;
        acc[3] = __builtin_amdgcn_mfma_f32_32x32x16_bf16(paf[1], uv.s, acc[3], 0, 0, 0); }
    }
  }
#pragma unroll
  for (int dt = 0; dt < 4; ++dt) {
#pragma unroll
    for (int r = 0; r < 16; ++r) {
      int q = (r & 3) + 8 * (r >> 2) + 4 * hi;
      int gi = i0 + w * 32 + q;
      if (gi < SEQN)
        av[(actB + gi) * DD + h * HD + dt * 32 + lo31] = f2bf(acc[dt][r]);
    }
  }
}

// ---------------- launch ----------------
extern "C" void kernel_launch(void* const* d_in, const int* in_sizes, int n_in,
                              void* d_out, int out_size, void* d_ws, size_t ws_size,
                              hipStream_t stream) {
  const float* seqs  = (const float*)d_in[0];
  const int*   ts    = (const int*)d_in[2];
  const float* qkvuW = (const float*)d_in[3];
  const float* outW  = (const float*)d_in[4];
  const float* outB  = (const float*)d_in[5];
  const float* tsW   = (const float*)d_in[6];
  const float* posW  = (const float*)d_in[7];
  const float* fc1W  = (const float*)d_in[8];
  const float* fc1B  = (const float*)d_in[9];
  const float* fc2W  = (const float*)d_in[10];
  const float* fc2B  = (const float*)d_in[11];
  float* h = (float*)d_out;
  char* ws = (char*)d_ws;

  // ws layout (16B-aligned).  av aliases the gated region (av dead before fc1
  // writes gated; stream-ordered).  Double-buffered weights/bias per layer.
  ushort* xn     = (ushort*)(ws);                 // 8448*1024*2   = 17,301,504
  ushort* act    = (ushort*)(ws + 17301504);      // 8200*4096*2   = 67,174,400
  ushort* gated  = (ushort*)(ws + 84475904);      // 8320*2048*2   = 34,078,720
  ushort* av     = gated;                         // alias (16,793,600 <= 34,078,720)
  ushort* biasT0 = (ushort*)(ws + 118554624);     // 16,810,240 (rounded)
  ushort* biasT1 = (ushort*)(ws + 135364864);     // 16,810,240
  ushort* wq0    = (ushort*)(ws + 152175104);     // 8,388,608
  ushort* wo0    = (ushort*)(ws + 160563712);     // 2,097,152
  ushort* wf10   = (ushort*)(ws + 162660864);     // 8,388,608
  ushort* wf20   = (ushort*)(ws + 171049472);     // 4,194,304
  ushort* wq1    = (ushort*)(ws + 175243776);     // 8,388,608
  ushort* wo1    = (ushort*)(ws + 183632384);     // 2,097,152
  ushort* wf11   = (ushort*)(ws + 185729536);     // 8,388,608
  ushort* wf21   = (ushort*)(ws + 194118144);     // 4,194,304  (end 198,312,448)

  // ONE front dispatch: both layers' weight transposes + bias tables + layer-0 lnh
  prep2_kernel<<<106578, 256, 0, stream>>>(
      qkvuW, outW, fc1W, fc2W,
      wq0, wo0, wf10, wf20, wq1, wo1, wf11, wf21,
      ts, tsW, posW, biasT0, biasT1,
      seqs, h, xn);

  for (int l = 0; l < LL; l++) {
    ushort* wq  = l ? wq1  : wq0;
    ushort* wo  = l ? wo1  : wo0;
    ushort* wf1 = l ? wf11 : wf10;
    ushort* wf2 = l ? wf21 : wf20;
    ushort* bT  = l ? biasT1 : biasT0;

    if (l > 0)
      ln_kernel<<<MROWS / 4, 256, 0, stream>>>(h, xn);
    mgemm8<0><<<dim3(16, 33), 512, 0, stream>>>(xn, wq, nullptr, act, MROWS, 4096, DD);
    attn_kernel<<<dim3(9, HH, BB), 256, 0, stream>>>(act, bT, av);
    uln_kernel<<<MROWS / 4, 256, 0, stream>>>(av, act, xn);
    mgemm1<<<dim3(8, 65), 256, 0, stream>>>(xn, wo, outB + l * DD, h, MROWS, DD, DD);
    rms_kernel<<<MROWS / 4, 256, 0, stream>>>(h, xn);
    mgemm8<3><<<dim3(16, 33), 512, 0, stream>>>(xn, wf1, fc1B + (size_t)l * 4096, gated, MROWS, 2048, DD);
    mgemm1<<<dim3(8, 65), 256, 0, stream>>>(gated, wf2, fc2B + l * DD, h, MROWS, DD, 2048);
  }
}